// Round 3
// baseline (1079.476 us; speedup 1.0000x reference)
//
#include <hip/hip_runtime.h>

#define NPIX 704
#define NIMG 24
#define NB 4
#define NCAM 6
#define DB 59
#define CT 64
#define P_TOT (NIMG*NPIX*DB)   // 996864
#define NVOX 65536             // 4 batches * 128*128 (gz==0 only)

// ---------------------------------------------------------------------------
// Kernel 1: per-(b,n) matrix prep.
// ---------------------------------------------------------------------------
__device__ inline void inv3(const double a[9], double o[9]) {
  double c0 = a[4]*a[8] - a[5]*a[7];
  double c1 = a[3]*a[8] - a[5]*a[6];
  double c2 = a[3]*a[7] - a[4]*a[6];
  double det = a[0]*c0 - a[1]*c1 + a[2]*c2;
  double id = 1.0 / det;
  o[0] =  c0 * id;
  o[1] = (a[2]*a[7] - a[1]*a[8]) * id;
  o[2] = (a[1]*a[5] - a[2]*a[4]) * id;
  o[3] = -c1 * id;
  o[4] = (a[0]*a[8] - a[2]*a[6]) * id;
  o[5] = (a[2]*a[3] - a[0]*a[5]) * id;
  o[6] =  c2 * id;
  o[7] = (a[1]*a[6] - a[0]*a[7]) * id;
  o[8] = (a[0]*a[4] - a[1]*a[3]) * id;
}

__global__ void prep_mats(const float* __restrict__ rots, const float* __restrict__ trans,
                          const float* __restrict__ intr, const float* __restrict__ prot,
                          const float* __restrict__ ptra, float* __restrict__ mats) {
  int bn = threadIdx.x;
  if (bn >= NIMG) return;
  double pr[9], ik[9];
  for (int i = 0; i < 9; i++) { pr[i] = prot[bn*9 + i]; ik[i] = intr[bn*9 + i]; }
  double Minv[9], Kinv[9];
  inv3(pr, Minv);
  inv3(ik, Kinv);
  float* m = mats + bn*24;
  for (int i = 0; i < 9; i++) m[i] = (float)Minv[i];
  float kf[9];
  for (int i = 0; i < 9; i++) kf[i] = (float)Kinv[i];
  {
#pragma clang fp contract(off)
    for (int i = 0; i < 3; i++)
      for (int j = 0; j < 3; j++) {
        float s = rots[bn*9 + i*3 + 0] * kf[0*3 + j];
        s = s + rots[bn*9 + i*3 + 1] * kf[1*3 + j];
        s = s + rots[bn*9 + i*3 + 2] * kf[2*3 + j];
        m[9 + i*3 + j] = s;
      }
  }
  m[18] = ptra[bn*3 + 0]; m[19] = ptra[bn*3 + 1]; m[20] = ptra[bn*3 + 2];
  m[21] = trans[bn*3 + 0]; m[22] = trans[bn*3 + 1]; m[23] = trans[bn*3 + 2];
}

// ---------------------------------------------------------------------------
// Kernel 2: feat = W_depth @ x, softmax over first 59 channels.
// ---------------------------------------------------------------------------
__global__ __launch_bounds__(256) void gemm_softmax(const float* __restrict__ x,
    const float* __restrict__ Wd, const float* __restrict__ bd,
    float* __restrict__ depth_ws, float* __restrict__ img_ws) {
  __shared__ float smem[64*68 + 64*132];
  __shared__ float sm[64], ss[64];
  float* Xt = smem;
  float* Wt = smem + 64*68;
  int t = threadIdx.x;
  int blk = blockIdx.x;
  int bn = blk / 11, tile = blk - bn*11;
  int pixbase = tile * 64;
  const float* xim = x + (size_t)bn * 512 * NPIX + pixbase;
  int pg = t & 15, og = t >> 4;
  int p0 = pg << 2, o0 = og << 3;
  float acc[8][4];
  for (int i = 0; i < 8; i++) for (int j = 0; j < 4; j++) acc[i][j] = 0.f;

  for (int kc = 0; kc < 512; kc += 64) {
    for (int i = 0; i < 16; i++) {
      int cl = (t >> 6) + (i << 2);
      Xt[cl*68 + (t & 63)] = xim[(size_t)(kc + cl) * NPIX + (t & 63)];
    }
    for (int i = 0; i < 32; i++) {
      int idx = t + (i << 8);
      int o = idx >> 6, k = idx & 63;
      Wt[k*132 + o] = (o < 123) ? Wd[o*512 + kc + k] : 0.f;
    }
    __syncthreads();
#pragma unroll 8
    for (int k = 0; k < 64; k++) {
      const float4 a  = *(const float4*)&Xt[k*68 + p0];
      const float4 w0 = *(const float4*)&Wt[k*132 + o0];
      const float4 w1 = *(const float4*)&Wt[k*132 + o0 + 4];
      float av[4] = {a.x, a.y, a.z, a.w};
      float wv[8] = {w0.x, w0.y, w0.z, w0.w, w1.x, w1.y, w1.z, w1.w};
      for (int oi = 0; oi < 8; oi++)
        for (int pi = 0; pi < 4; pi++)
          acc[oi][pi] += wv[oi] * av[pi];
    }
    __syncthreads();
  }

  float* F = smem;
  for (int oi = 0; oi < 8; oi++) {
    int o = o0 + oi;
    float b = (o < 123) ? bd[o] : 0.f;
    for (int pi = 0; pi < 4; pi++) F[o*68 + p0 + pi] = acc[oi][pi] + b;
  }
  __syncthreads();

  {
    int pix = t & 63;
    float mmax = -3.4e38f;
    for (int d = 0; d < DB; d++) mmax = fmaxf(mmax, F[d*68 + pix]);
    float s = 0.f;
    for (int d = 0; d < DB; d++) s += expf(F[d*68 + pix] - mmax);
    if (t < 64) { sm[t] = mmax; ss[t] = s; }
  }
  __syncthreads();

  {
    int c = t & 63;
    for (int p = t >> 6; p < 64; p += 4) {
      size_t rec = (size_t)(bn*NPIX + pixbase + p) * 64;
      if (c < DB) depth_ws[rec + c] = expf(F[c*68 + p] - sm[p]) / ss[p];
      img_ws[rec + c] = F[(DB + c)*68 + p];
    }
  }
}

// ---------------------------------------------------------------------------
// Kernel 3: geometry -> voxel code per point + histogram.
// point index p = bnpix*59 + d; code = b*16384 + gy*128 + gx (or -1)
// ---------------------------------------------------------------------------
__global__ __launch_bounds__(256) void geom_k(const float* __restrict__ mats,
    int* __restrict__ codes, int* __restrict__ hist) {
  int wid = (blockIdx.x << 2) + (threadIdx.x >> 6);
  int lane = threadIdx.x & 63;
  int bn = wid / NPIX;
  int pix = wid - bn*NPIX;
  int b = bn / NCAM;
  int h = pix / 44, w = pix - h*44;
  const float* M = mats + bn*24;

  int code = -1;
  {
#pragma clang fp contract(off)
    float xs = (float)((double)w * (703.0 / 43.0));
    float ys = (float)(h * 17);
    float dval = (float)(lane + 1);
    float vx = xs - M[18], vy = ys - M[19], vz = dval - M[20];
    float qx = M[0]*vx + M[1]*vy + M[2]*vz;
    float qy = M[3]*vx + M[4]*vy + M[5]*vz;
    float qz = M[6]*vx + M[7]*vy + M[8]*vz;
    float rx = qx*qz, ry = qy*qz;
    float px = M[9]*rx  + M[10]*ry + M[11]*qz + M[21];
    float py = M[12]*rx + M[13]*ry + M[14]*qz + M[22];
    float pz = M[15]*rx + M[16]*ry + M[17]*qz + M[23];
    float gx = floorf((px - (-50.8f - 0.4f)) / 0.8f);
    float gy = floorf((py - (-50.8f - 0.4f)) / 0.8f);
    float gz = floorf((pz - (0.0f - 10.0f)) / 20.0f);
    bool kept = (lane < DB) && (gx >= 0.f) && (gx < 128.f) &&
                (gy >= 0.f) && (gy < 128.f) && (gz == 0.f);
    if (kept) code = (b << 14) + (int)gy * 128 + (int)gx;
  }

  if (lane < DB) {
    codes[(size_t)wid * DB + lane] = code;
    if (code >= 0) atomicAdd(&hist[code], 1);
  }
}

// ---------------------------------------------------------------------------
// Kernel 4: exclusive scan of hist[65536] -> offsets, cursor (one block).
// ---------------------------------------------------------------------------
__global__ __launch_bounds__(1024) void scan_k(const int* __restrict__ hist,
    int* __restrict__ offsets, int* __restrict__ cursor) {
  __shared__ int psum[1024];
  int t = threadIdx.x;
  int base = t << 6;
  int loc[64];
  int s = 0;
#pragma unroll
  for (int i = 0; i < 64; i++) { loc[i] = hist[base + i]; s += loc[i]; }
  psum[t] = s;
  __syncthreads();
  if (t == 0) {
    int r = 0;
    for (int i = 0; i < 1024; i++) { int v = psum[i]; psum[i] = r; r += v; }
  }
  __syncthreads();
  int run = psum[t];
#pragma unroll
  for (int i = 0; i < 64; i++) {
    offsets[base + i] = run;
    cursor[base + i] = run;
    run += loc[i];
  }
}

// ---------------------------------------------------------------------------
// Kernel 5: bucket-place point indices.
// ---------------------------------------------------------------------------
__global__ __launch_bounds__(256) void order_k(const int* __restrict__ codes,
    int* __restrict__ cursor, int* __restrict__ order) {
  int p = blockIdx.x * 256 + threadIdx.x;
  if (p >= P_TOT) return;
  int c = codes[p];
  if (c >= 0) {
    int pos = atomicAdd(&cursor[c], 1);
    order[pos] = p;
  }
}

// ---------------------------------------------------------------------------
// Kernel 6: gather. One wave per voxel, lane = channel. No float atomics.
// ---------------------------------------------------------------------------
__global__ __launch_bounds__(256) void gather_k(const int* __restrict__ offsets,
    const int* __restrict__ cursor, const int* __restrict__ order,
    const float* __restrict__ depth_ws, const float* __restrict__ img_ws,
    float* __restrict__ out) {
  int wid = (blockIdx.x << 2) + (threadIdx.x >> 6);   // voxel 0..65535
  int lane = threadIdx.x & 63;
  int b = wid >> 14, vox = wid & 16383;
  int start = offsets[wid], end = cursor[wid];
  float acc = 0.f;
  for (int i = start; i < end; ++i) {
    int p = order[i];
    int bnpix = p / DB;
    int d = p - bnpix * DB;
    float wgt = depth_ws[(size_t)bnpix * 64 + d];
    float im  = img_ws[(size_t)bnpix * 64 + lane];
    acc += wgt * im;
  }
  out[((size_t)(b * 64 + lane) << 14) + vox] = acc;
}

// ---------------------------------------------------------------------------
extern "C" void kernel_launch(void* const* d_in, const int* in_sizes, int n_in,
                              void* d_out, int out_size, void* d_ws, size_t ws_size,
                              hipStream_t stream) {
  const float* x    = (const float*)d_in[0];
  const float* rots = (const float*)d_in[1];
  const float* trn  = (const float*)d_in[2];
  const float* intr = (const float*)d_in[3];
  const float* prot = (const float*)d_in[4];
  const float* ptra = (const float*)d_in[5];
  const float* Wd   = (const float*)d_in[6];
  const float* bd   = (const float*)d_in[7];
  float* out = (float*)d_out;
  float* ws  = (float*)d_ws;

  float* mats     = ws;                                   // 1024 floats (576 used)
  float* depth_ws = ws + 1024;                            // 1,081,344
  float* img_ws   = depth_ws + (size_t)NIMG*NPIX*64;      // 1,081,344
  int*   hist     = (int*)(img_ws + (size_t)NIMG*NPIX*64);// 65536
  int*   offsets  = hist + NVOX;                          // 65536
  int*   cursor   = offsets + NVOX;                       // 65536
  int*   codes    = cursor + NVOX;                        // 996,864
  int*   order    = codes + P_TOT;                        // 996,864

  (void)hipMemsetAsync(hist, 0, NVOX * sizeof(int), stream);
  prep_mats<<<1, 32, 0, stream>>>(rots, trn, intr, prot, ptra, mats);
  gemm_softmax<<<NIMG*11, 256, 0, stream>>>(x, Wd, bd, depth_ws, img_ws);
  geom_k<<<NIMG*NPIX/4, 256, 0, stream>>>(mats, codes, hist);
  scan_k<<<1, 1024, 0, stream>>>(hist, offsets, cursor);
  order_k<<<(P_TOT + 255)/256, 256, 0, stream>>>(codes, cursor, order);
  gather_k<<<NVOX/4, 256, 0, stream>>>(offsets, cursor, order, depth_ws, img_ws, out);
}

// Round 4
// 417.851 us; speedup vs baseline: 2.5834x; 2.5834x over previous
//
#include <hip/hip_runtime.h>

#define NPIX 704
#define NIMG 24
#define NB 4
#define NCAM 6
#define DB 59
#define CT 64
#define P_TOT (NIMG*NPIX*DB)   // 996864
#define NVOX 65536             // 4 batches * 128*128 (gz==0 only)
#define CHUNK 64

// ---------------------------------------------------------------------------
// Kernel 1: per-(b,n) matrix prep.
// ---------------------------------------------------------------------------
__device__ inline void inv3(const double a[9], double o[9]) {
  double c0 = a[4]*a[8] - a[5]*a[7];
  double c1 = a[3]*a[8] - a[5]*a[6];
  double c2 = a[3]*a[7] - a[4]*a[6];
  double det = a[0]*c0 - a[1]*c1 + a[2]*c2;
  double id = 1.0 / det;
  o[0] =  c0 * id;
  o[1] = (a[2]*a[7] - a[1]*a[8]) * id;
  o[2] = (a[1]*a[5] - a[2]*a[4]) * id;
  o[3] = -c1 * id;
  o[4] = (a[0]*a[8] - a[2]*a[6]) * id;
  o[5] = (a[2]*a[3] - a[0]*a[5]) * id;
  o[6] =  c2 * id;
  o[7] = (a[1]*a[6] - a[0]*a[7]) * id;
  o[8] = (a[0]*a[4] - a[1]*a[3]) * id;
}

__global__ void prep_mats(const float* __restrict__ rots, const float* __restrict__ trans,
                          const float* __restrict__ intr, const float* __restrict__ prot,
                          const float* __restrict__ ptra, float* __restrict__ mats) {
  int bn = threadIdx.x;
  if (bn >= NIMG) return;
  double pr[9], ik[9];
  for (int i = 0; i < 9; i++) { pr[i] = prot[bn*9 + i]; ik[i] = intr[bn*9 + i]; }
  double Minv[9], Kinv[9];
  inv3(pr, Minv);
  inv3(ik, Kinv);
  float* m = mats + bn*24;
  for (int i = 0; i < 9; i++) m[i] = (float)Minv[i];
  float kf[9];
  for (int i = 0; i < 9; i++) kf[i] = (float)Kinv[i];
  {
#pragma clang fp contract(off)
    for (int i = 0; i < 3; i++)
      for (int j = 0; j < 3; j++) {
        float s = rots[bn*9 + i*3 + 0] * kf[0*3 + j];
        s = s + rots[bn*9 + i*3 + 1] * kf[1*3 + j];
        s = s + rots[bn*9 + i*3 + 2] * kf[2*3 + j];
        m[9 + i*3 + j] = s;
      }
  }
  m[18] = ptra[bn*3 + 0]; m[19] = ptra[bn*3 + 1]; m[20] = ptra[bn*3 + 2];
  m[21] = trans[bn*3 + 0]; m[22] = trans[bn*3 + 1]; m[23] = trans[bn*3 + 2];
}

// ---------------------------------------------------------------------------
// Kernel 2: feat = W_depth @ x, softmax over first 59 channels.
// ---------------------------------------------------------------------------
__global__ __launch_bounds__(256) void gemm_softmax(const float* __restrict__ x,
    const float* __restrict__ Wd, const float* __restrict__ bd,
    float* __restrict__ depth_ws, float* __restrict__ img_ws) {
  __shared__ float smem[64*68 + 64*132];
  __shared__ float sm[64], ss[64];
  float* Xt = smem;
  float* Wt = smem + 64*68;
  int t = threadIdx.x;
  int blk = blockIdx.x;
  int bn = blk / 11, tile = blk - bn*11;
  int pixbase = tile * 64;
  const float* xim = x + (size_t)bn * 512 * NPIX + pixbase;
  int pg = t & 15, og = t >> 4;
  int p0 = pg << 2, o0 = og << 3;
  float acc[8][4];
  for (int i = 0; i < 8; i++) for (int j = 0; j < 4; j++) acc[i][j] = 0.f;

  for (int kc = 0; kc < 512; kc += 64) {
    for (int i = 0; i < 16; i++) {
      int cl = (t >> 6) + (i << 2);
      Xt[cl*68 + (t & 63)] = xim[(size_t)(kc + cl) * NPIX + (t & 63)];
    }
    for (int i = 0; i < 32; i++) {
      int idx = t + (i << 8);
      int o = idx >> 6, k = idx & 63;
      Wt[k*132 + o] = (o < 123) ? Wd[o*512 + kc + k] : 0.f;
    }
    __syncthreads();
#pragma unroll 8
    for (int k = 0; k < 64; k++) {
      const float4 a  = *(const float4*)&Xt[k*68 + p0];
      const float4 w0 = *(const float4*)&Wt[k*132 + o0];
      const float4 w1 = *(const float4*)&Wt[k*132 + o0 + 4];
      float av[4] = {a.x, a.y, a.z, a.w};
      float wv[8] = {w0.x, w0.y, w0.z, w0.w, w1.x, w1.y, w1.z, w1.w};
      for (int oi = 0; oi < 8; oi++)
        for (int pi = 0; pi < 4; pi++)
          acc[oi][pi] += wv[oi] * av[pi];
    }
    __syncthreads();
  }

  float* F = smem;
  for (int oi = 0; oi < 8; oi++) {
    int o = o0 + oi;
    float b = (o < 123) ? bd[o] : 0.f;
    for (int pi = 0; pi < 4; pi++) F[o*68 + p0 + pi] = acc[oi][pi] + b;
  }
  __syncthreads();

  {
    int pix = t & 63;
    float mmax = -3.4e38f;
    for (int d = 0; d < DB; d++) mmax = fmaxf(mmax, F[d*68 + pix]);
    float s = 0.f;
    for (int d = 0; d < DB; d++) s += expf(F[d*68 + pix] - mmax);
    if (t < 64) { sm[t] = mmax; ss[t] = s; }
  }
  __syncthreads();

  {
    int c = t & 63;
    for (int p = t >> 6; p < 64; p += 4) {
      size_t rec = (size_t)(bn*NPIX + pixbase + p) * 64;
      if (c < DB) depth_ws[rec + c] = expf(F[c*68 + p] - sm[p]) / ss[p];
      img_ws[rec + c] = F[(DB + c)*68 + p];
    }
  }
}

// ---------------------------------------------------------------------------
// Kernel 3: geometry -> voxel code per point + histogram.
// ---------------------------------------------------------------------------
__global__ __launch_bounds__(256) void geom_k(const float* __restrict__ mats,
    int* __restrict__ codes, int* __restrict__ hist) {
  int wid = (blockIdx.x << 2) + (threadIdx.x >> 6);
  int lane = threadIdx.x & 63;
  int bn = wid / NPIX;
  int pix = wid - bn*NPIX;
  int b = bn / NCAM;
  int h = pix / 44, w = pix - h*44;
  const float* M = mats + bn*24;

  int code = -1;
  {
#pragma clang fp contract(off)
    float xs = (float)((double)w * (703.0 / 43.0));
    float ys = (float)(h * 17);
    float dval = (float)(lane + 1);
    float vx = xs - M[18], vy = ys - M[19], vz = dval - M[20];
    float qx = M[0]*vx + M[1]*vy + M[2]*vz;
    float qy = M[3]*vx + M[4]*vy + M[5]*vz;
    float qz = M[6]*vx + M[7]*vy + M[8]*vz;
    float rx = qx*qz, ry = qy*qz;
    float px = M[9]*rx  + M[10]*ry + M[11]*qz + M[21];
    float py = M[12]*rx + M[13]*ry + M[14]*qz + M[22];
    float pz = M[15]*rx + M[16]*ry + M[17]*qz + M[23];
    float gx = floorf((px - (-50.8f - 0.4f)) / 0.8f);
    float gy = floorf((py - (-50.8f - 0.4f)) / 0.8f);
    float gz = floorf((pz - (0.0f - 10.0f)) / 20.0f);
    bool kept = (lane < DB) && (gx >= 0.f) && (gx < 128.f) &&
                (gy >= 0.f) && (gy < 128.f) && (gz == 0.f);
    if (kept) code = (b << 14) + (int)gy * 128 + (int)gx;
  }

  if (lane < DB) {
    codes[(size_t)wid * DB + lane] = code;
    if (code >= 0) atomicAdd(&hist[code], 1);
  }
}

// ---------------------------------------------------------------------------
// Kernel 4: exclusive scan of hist[65536] (one block, parallel scan).
// ---------------------------------------------------------------------------
__global__ __launch_bounds__(1024) void scan_k(const int* __restrict__ hist,
    int* __restrict__ offsets, int* __restrict__ cursor, int* __restrict__ totalK) {
  __shared__ int buf[2][1024];
  int t = threadIdx.x;
  int base = t << 6;
  int loc[64];
  int s = 0;
#pragma unroll
  for (int i = 0; i < 64; i++) { loc[i] = hist[base + i]; s += loc[i]; }
  buf[0][t] = s;
  __syncthreads();
  int src = 0;
  for (int ofs = 1; ofs < 1024; ofs <<= 1) {
    int v = buf[src][t];
    if (t >= ofs) v += buf[src][t - ofs];
    buf[src ^ 1][t] = v;
    __syncthreads();
    src ^= 1;
  }
  int run = (t == 0) ? 0 : buf[src][t - 1];
  if (t == 1023) *totalK = buf[src][1023];
#pragma unroll
  for (int i = 0; i < 64; i++) {
    offsets[base + i] = run;
    cursor[base + i] = run;
    run += loc[i];
  }
}

// ---------------------------------------------------------------------------
// Kernel 5: bucket-place points: sorted[pos] = {code, bnpix*64 + d}
// ---------------------------------------------------------------------------
__global__ __launch_bounds__(256) void order_k(const int* __restrict__ codes,
    int* __restrict__ cursor, int2* __restrict__ sorted) {
  int p = blockIdx.x * 256 + threadIdx.x;
  if (p >= P_TOT) return;
  int c = codes[p];
  if (c >= 0) {
    int bnpix = p / DB;
    int d = p - bnpix * DB;
    int pos = atomicAdd(&cursor[c], 1);
    sorted[pos] = make_int2(c, (bnpix << 6) + d);
  }
}

// ---------------------------------------------------------------------------
// Kernel 6: segmented gather. One wave per CHUNK sorted points; lane = channel.
// Flush partial sums with atomicAdd only at segment boundaries.
// ---------------------------------------------------------------------------
__global__ __launch_bounds__(256) void gather_seg(const int2* __restrict__ sorted,
    const int* __restrict__ totalK,
    const float* __restrict__ depth_ws, const float* __restrict__ img_ws,
    float* __restrict__ out) {
  int wid = (blockIdx.x << 2) + (threadIdx.x >> 6);
  int lane = threadIdx.x & 63;
  int K = *totalK;
  int start = wid * CHUNK;
  if (start >= K) return;
  int end = min(start + CHUNK, K);

  int2 s0 = sorted[start];
  int cur = s0.x;
  float acc = 0.f;
  for (int i = start; i < end; ++i) {
    int2 s = sorted[i];
    if (s.x != cur) {                     // wave-uniform branch
      int b = cur >> 14, vox = cur & 16383;
      unsafeAtomicAdd(&out[((size_t)((b << 6) + lane) << 14) + vox], acc);
      acc = 0.f;
      cur = s.x;
    }
    float dep = depth_ws[s.y];                          // broadcast load
    float im  = img_ws[(s.y & 0x7FFFFFC0) + lane];      // coalesced 256B
    acc += dep * im;
  }
  int b = cur >> 14, vox = cur & 16383;
  unsafeAtomicAdd(&out[((size_t)((b << 6) + lane) << 14) + vox], acc);
}

// ---------------------------------------------------------------------------
extern "C" void kernel_launch(void* const* d_in, const int* in_sizes, int n_in,
                              void* d_out, int out_size, void* d_ws, size_t ws_size,
                              hipStream_t stream) {
  const float* x    = (const float*)d_in[0];
  const float* rots = (const float*)d_in[1];
  const float* trn  = (const float*)d_in[2];
  const float* intr = (const float*)d_in[3];
  const float* prot = (const float*)d_in[4];
  const float* ptra = (const float*)d_in[5];
  const float* Wd   = (const float*)d_in[6];
  const float* bd   = (const float*)d_in[7];
  float* out = (float*)d_out;
  float* ws  = (float*)d_ws;

  float* mats     = ws;                                    // 1024
  float* depth_ws = ws + 1024;                             // 1,081,344
  float* img_ws   = depth_ws + (size_t)NIMG*NPIX*64;       // 1,081,344
  int*   hist     = (int*)(img_ws + (size_t)NIMG*NPIX*64); // 65536
  int*   offsets  = hist + NVOX;                           // 65536
  int*   cursor   = offsets + NVOX;                        // 65536
  int*   totalK   = cursor + NVOX;                         // 2 (pad for int2 align)
  int2*  sorted   = (int2*)(totalK + 2);                   // 996,864 int2
  int*   codes    = (int*)(sorted + P_TOT);                // 996,864

  (void)hipMemsetAsync(hist, 0, NVOX * sizeof(int), stream);
  (void)hipMemsetAsync(d_out, 0, (size_t)out_size * sizeof(float), stream);
  prep_mats<<<1, 32, 0, stream>>>(rots, trn, intr, prot, ptra, mats);
  gemm_softmax<<<NIMG*11, 256, 0, stream>>>(x, Wd, bd, depth_ws, img_ws);
  geom_k<<<NIMG*NPIX/4, 256, 0, stream>>>(mats, codes, hist);
  scan_k<<<1, 1024, 0, stream>>>(hist, offsets, cursor, totalK);
  order_k<<<(P_TOT + 255)/256, 256, 0, stream>>>(codes, cursor, sorted);
  gather_seg<<<(P_TOT/CHUNK + 3)/4, 256, 0, stream>>>(sorted, totalK, depth_ws, img_ws, out);
}

// Round 5
// 362.951 us; speedup vs baseline: 2.9742x; 1.1513x over previous
//
#include <hip/hip_runtime.h>

#define NPIX 704
#define NIMG 24
#define NB 4
#define NCAM 6
#define DB 59
#define CT 64
#define P_TOT (NIMG*NPIX*DB)   // 996864
#define NVOX 65536             // 4 batches * 128*128 (gz==0 only)
#define SLC 8                  // histogram slices (contention spreading)
#define NKEY (NVOX*SLC)        // 524288
#define CHUNK 64

// ---------------------------------------------------------------------------
// Kernel 1: per-(b,n) matrix prep.
// ---------------------------------------------------------------------------
__device__ inline void inv3(const double a[9], double o[9]) {
  double c0 = a[4]*a[8] - a[5]*a[7];
  double c1 = a[3]*a[8] - a[5]*a[6];
  double c2 = a[3]*a[7] - a[4]*a[6];
  double det = a[0]*c0 - a[1]*c1 + a[2]*c2;
  double id = 1.0 / det;
  o[0] =  c0 * id;
  o[1] = (a[2]*a[7] - a[1]*a[8]) * id;
  o[2] = (a[1]*a[5] - a[2]*a[4]) * id;
  o[3] = -c1 * id;
  o[4] = (a[0]*a[8] - a[2]*a[6]) * id;
  o[5] = (a[2]*a[3] - a[0]*a[5]) * id;
  o[6] =  c2 * id;
  o[7] = (a[1]*a[6] - a[0]*a[7]) * id;
  o[8] = (a[0]*a[4] - a[1]*a[3]) * id;
}

__global__ void prep_mats(const float* __restrict__ rots, const float* __restrict__ trans,
                          const float* __restrict__ intr, const float* __restrict__ prot,
                          const float* __restrict__ ptra, float* __restrict__ mats) {
  int bn = threadIdx.x;
  if (bn >= NIMG) return;
  double pr[9], ik[9];
  for (int i = 0; i < 9; i++) { pr[i] = prot[bn*9 + i]; ik[i] = intr[bn*9 + i]; }
  double Minv[9], Kinv[9];
  inv3(pr, Minv);
  inv3(ik, Kinv);
  float* m = mats + bn*24;
  for (int i = 0; i < 9; i++) m[i] = (float)Minv[i];
  float kf[9];
  for (int i = 0; i < 9; i++) kf[i] = (float)Kinv[i];
  {
#pragma clang fp contract(off)
    for (int i = 0; i < 3; i++)
      for (int j = 0; j < 3; j++) {
        float s = rots[bn*9 + i*3 + 0] * kf[0*3 + j];
        s = s + rots[bn*9 + i*3 + 1] * kf[1*3 + j];
        s = s + rots[bn*9 + i*3 + 2] * kf[2*3 + j];
        m[9 + i*3 + j] = s;
      }
  }
  m[18] = ptra[bn*3 + 0]; m[19] = ptra[bn*3 + 1]; m[20] = ptra[bn*3 + 2];
  m[21] = trans[bn*3 + 0]; m[22] = trans[bn*3 + 1]; m[23] = trans[bn*3 + 2];
}

// ---------------------------------------------------------------------------
// Kernel 2: feat = W_depth @ x, softmax over first 59 channels.
// ---------------------------------------------------------------------------
__global__ __launch_bounds__(256) void gemm_softmax(const float* __restrict__ x,
    const float* __restrict__ Wd, const float* __restrict__ bd,
    float* __restrict__ depth_ws, float* __restrict__ img_ws) {
  __shared__ float smem[64*68 + 64*132];
  __shared__ float sm[64], ss[64];
  float* Xt = smem;
  float* Wt = smem + 64*68;
  int t = threadIdx.x;
  int blk = blockIdx.x;
  int bn = blk / 11, tile = blk - bn*11;
  int pixbase = tile * 64;
  const float* xim = x + (size_t)bn * 512 * NPIX + pixbase;
  int pg = t & 15, og = t >> 4;
  int p0 = pg << 2, o0 = og << 3;
  float acc[8][4];
  for (int i = 0; i < 8; i++) for (int j = 0; j < 4; j++) acc[i][j] = 0.f;

  for (int kc = 0; kc < 512; kc += 64) {
    for (int i = 0; i < 16; i++) {
      int cl = (t >> 6) + (i << 2);
      Xt[cl*68 + (t & 63)] = xim[(size_t)(kc + cl) * NPIX + (t & 63)];
    }
    for (int i = 0; i < 32; i++) {
      int idx = t + (i << 8);
      int o = idx >> 6, k = idx & 63;
      Wt[k*132 + o] = (o < 123) ? Wd[o*512 + kc + k] : 0.f;
    }
    __syncthreads();
#pragma unroll 8
    for (int k = 0; k < 64; k++) {
      const float4 a  = *(const float4*)&Xt[k*68 + p0];
      const float4 w0 = *(const float4*)&Wt[k*132 + o0];
      const float4 w1 = *(const float4*)&Wt[k*132 + o0 + 4];
      float av[4] = {a.x, a.y, a.z, a.w};
      float wv[8] = {w0.x, w0.y, w0.z, w0.w, w1.x, w1.y, w1.z, w1.w};
      for (int oi = 0; oi < 8; oi++)
        for (int pi = 0; pi < 4; pi++)
          acc[oi][pi] += wv[oi] * av[pi];
    }
    __syncthreads();
  }

  float* F = smem;
  for (int oi = 0; oi < 8; oi++) {
    int o = o0 + oi;
    float b = (o < 123) ? bd[o] : 0.f;
    for (int pi = 0; pi < 4; pi++) F[o*68 + p0 + pi] = acc[oi][pi] + b;
  }
  __syncthreads();

  {
    int pix = t & 63;
    float mmax = -3.4e38f;
    for (int d = 0; d < DB; d++) mmax = fmaxf(mmax, F[d*68 + pix]);
    float s = 0.f;
    for (int d = 0; d < DB; d++) s += expf(F[d*68 + pix] - mmax);
    if (t < 64) { sm[t] = mmax; ss[t] = s; }
  }
  __syncthreads();

  {
    int c = t & 63;
    for (int p = t >> 6; p < 64; p += 4) {
      size_t rec = (size_t)(bn*NPIX + pixbase + p) * 64;
      if (c < DB) depth_ws[rec + c] = expf(F[c*68 + p] - sm[p]) / ss[p];
      img_ws[rec + c] = F[(DB + c)*68 + p];
    }
  }
}

// ---------------------------------------------------------------------------
// Kernel 3: geometry -> sliced key + rank via hist atomic (the ONLY contended
// atomic pass). key = code*SLC + slice, slice spreads hot buckets.
// ---------------------------------------------------------------------------
__global__ __launch_bounds__(256) void geom_k(const float* __restrict__ mats,
    int2* __restrict__ pr, int* __restrict__ hist) {
  int wid = (blockIdx.x << 2) + (threadIdx.x >> 6);
  int lane = threadIdx.x & 63;
  int bn = wid / NPIX;
  int pix = wid - bn*NPIX;
  int b = bn / NCAM;
  int h = pix / 44, w = pix - h*44;
  const float* M = mats + bn*24;

  int code = -1;
  {
#pragma clang fp contract(off)
    float xs = (float)((double)w * (703.0 / 43.0));
    float ys = (float)(h * 17);
    float dval = (float)(lane + 1);
    float vx = xs - M[18], vy = ys - M[19], vz = dval - M[20];
    float qx = M[0]*vx + M[1]*vy + M[2]*vz;
    float qy = M[3]*vx + M[4]*vy + M[5]*vz;
    float qz = M[6]*vx + M[7]*vy + M[8]*vz;
    float rx = qx*qz, ry = qy*qz;
    float px = M[9]*rx  + M[10]*ry + M[11]*qz + M[21];
    float py = M[12]*rx + M[13]*ry + M[14]*qz + M[22];
    float pz = M[15]*rx + M[16]*ry + M[17]*qz + M[23];
    float gx = floorf((px - (-50.8f - 0.4f)) / 0.8f);
    float gy = floorf((py - (-50.8f - 0.4f)) / 0.8f);
    float gz = floorf((pz - (0.0f - 10.0f)) / 20.0f);
    bool kept = (lane < DB) && (gx >= 0.f) && (gx < 128.f) &&
                (gy >= 0.f) && (gy < 128.f) && (gz == 0.f);
    if (kept) code = (b << 14) + (int)gy * 128 + (int)gx;
  }

  if (lane < DB) {
    int key = -1, r = 0;
    if (code >= 0) {
      key = code * SLC + ((wid + lane) & (SLC - 1));
      r = atomicAdd(&hist[key], 1);
    }
    pr[(size_t)wid * DB + lane] = make_int2(key, r);
  }
}

// ---------------------------------------------------------------------------
// Kernel 4: in-place exclusive scan of hist[NKEY] (one block, two passes).
// ---------------------------------------------------------------------------
__global__ __launch_bounds__(1024) void scan_k(int* __restrict__ hist,
    int* __restrict__ totalK) {
  __shared__ int buf[2][1024];
  const int PER = NKEY / 1024;   // 512
  int t = threadIdx.x;
  int base = t * PER;
  int s = 0;
  for (int i = 0; i < PER; i++) s += hist[base + i];
  buf[0][t] = s;
  __syncthreads();
  int src = 0;
  for (int ofs = 1; ofs < 1024; ofs <<= 1) {
    int v = buf[src][t];
    if (t >= ofs) v += buf[src][t - ofs];
    buf[src ^ 1][t] = v;
    __syncthreads();
    src ^= 1;
  }
  int run = (t == 0) ? 0 : buf[src][t - 1];
  if (t == 1023) *totalK = buf[src][1023];
  for (int i = 0; i < PER; i++) {
    int v = hist[base + i];
    hist[base + i] = run;
    run += v;
  }
}

// ---------------------------------------------------------------------------
// Kernel 5: atomic-free placement: pos = offsets[key] + rank.
// sorted[pos] = {code, bnpix*64 + d}
// ---------------------------------------------------------------------------
__global__ __launch_bounds__(256) void order_k(const int2* __restrict__ pr,
    const int* __restrict__ offsets, int2* __restrict__ sorted) {
  int p = blockIdx.x * 256 + threadIdx.x;
  if (p >= P_TOT) return;
  int2 e = pr[p];
  if (e.x >= 0) {
    int pos = offsets[e.x] + e.y;
    int bnpix = p / DB;
    int d = p - bnpix * DB;
    sorted[pos] = make_int2(e.x / SLC, (bnpix << 6) + d);
  }
}

// ---------------------------------------------------------------------------
// Kernel 6: segmented gather. One wave per CHUNK sorted points; lane = channel.
// ---------------------------------------------------------------------------
__global__ __launch_bounds__(256) void gather_seg(const int2* __restrict__ sorted,
    const int* __restrict__ totalK,
    const float* __restrict__ depth_ws, const float* __restrict__ img_ws,
    float* __restrict__ out) {
  int wid = (blockIdx.x << 2) + (threadIdx.x >> 6);
  int lane = threadIdx.x & 63;
  int K = *totalK;
  int start = wid * CHUNK;
  if (start >= K) return;
  int end = min(start + CHUNK, K);

  int2 s0 = sorted[start];
  int cur = s0.x;
  float acc = 0.f;
  for (int i = start; i < end; ++i) {
    int2 s = sorted[i];
    if (s.x != cur) {                     // wave-uniform branch
      int b = cur >> 14, vox = cur & 16383;
      unsafeAtomicAdd(&out[((size_t)((b << 6) + lane) << 14) + vox], acc);
      acc = 0.f;
      cur = s.x;
    }
    float dep = depth_ws[s.y];                          // broadcast load
    float im  = img_ws[(s.y & 0x7FFFFFC0) + lane];      // coalesced 256B
    acc += dep * im;
  }
  int b = cur >> 14, vox = cur & 16383;
  unsafeAtomicAdd(&out[((size_t)((b << 6) + lane) << 14) + vox], acc);
}

// ---------------------------------------------------------------------------
extern "C" void kernel_launch(void* const* d_in, const int* in_sizes, int n_in,
                              void* d_out, int out_size, void* d_ws, size_t ws_size,
                              hipStream_t stream) {
  const float* x    = (const float*)d_in[0];
  const float* rots = (const float*)d_in[1];
  const float* trn  = (const float*)d_in[2];
  const float* intr = (const float*)d_in[3];
  const float* prot = (const float*)d_in[4];
  const float* ptra = (const float*)d_in[5];
  const float* Wd   = (const float*)d_in[6];
  const float* bd   = (const float*)d_in[7];
  float* out = (float*)d_out;
  float* ws  = (float*)d_ws;

  float* mats     = ws;                                    // 1024 floats
  float* depth_ws = ws + 1024;                             // 1,081,344
  float* img_ws   = depth_ws + (size_t)NIMG*NPIX*64;       // 1,081,344
  int*   hist     = (int*)(img_ws + (size_t)NIMG*NPIX*64); // 524,288
  int*   totalK   = hist + NKEY;                           // 4 (pad)
  int2*  pr       = (int2*)(totalK + 4);                   // 996,864 int2
  int2*  sorted   = pr + P_TOT;                            // 996,864 int2

  (void)hipMemsetAsync(hist, 0, NKEY * sizeof(int), stream);
  (void)hipMemsetAsync(d_out, 0, (size_t)out_size * sizeof(float), stream);
  prep_mats<<<1, 32, 0, stream>>>(rots, trn, intr, prot, ptra, mats);
  gemm_softmax<<<NIMG*11, 256, 0, stream>>>(x, Wd, bd, depth_ws, img_ws);
  geom_k<<<NIMG*NPIX/4, 256, 0, stream>>>(mats, pr, hist);
  scan_k<<<1, 1024, 0, stream>>>(hist, totalK);
  order_k<<<(P_TOT + 255)/256, 256, 0, stream>>>(pr, hist, sorted);
  gather_seg<<<(P_TOT/CHUNK + 3)/4, 256, 0, stream>>>(sorted, totalK, depth_ws, img_ws, out);
}

// Round 6
// 173.378 us; speedup vs baseline: 6.2261x; 2.0934x over previous
//
#include <hip/hip_runtime.h>

#define NPIX 704
#define NIMG 24
#define NB 4
#define NCAM 6
#define DB 59
#define CT 64
#define P_TOT (NIMG*NPIX*DB)   // 996864
#define NVOX 65536             // 4 batches * 128*128 (gz==0 only)
#define SLC 8                  // histogram slices (contention spreading)
#define NKEY (NVOX*SLC)        // 524288
#define CHUNK 64
#define SCAN_BLKS 512          // NKEY / 1024

// ---------------------------------------------------------------------------
// Kernel 1: per-(b,n) matrix prep.
// ---------------------------------------------------------------------------
__device__ inline void inv3(const double a[9], double o[9]) {
  double c0 = a[4]*a[8] - a[5]*a[7];
  double c1 = a[3]*a[8] - a[5]*a[6];
  double c2 = a[3]*a[7] - a[4]*a[6];
  double det = a[0]*c0 - a[1]*c1 + a[2]*c2;
  double id = 1.0 / det;
  o[0] =  c0 * id;
  o[1] = (a[2]*a[7] - a[1]*a[8]) * id;
  o[2] = (a[1]*a[5] - a[2]*a[4]) * id;
  o[3] = -c1 * id;
  o[4] = (a[0]*a[8] - a[2]*a[6]) * id;
  o[5] = (a[2]*a[3] - a[0]*a[5]) * id;
  o[6] =  c2 * id;
  o[7] = (a[1]*a[6] - a[0]*a[7]) * id;
  o[8] = (a[0]*a[4] - a[1]*a[3]) * id;
}

__global__ void prep_mats(const float* __restrict__ rots, const float* __restrict__ trans,
                          const float* __restrict__ intr, const float* __restrict__ prot,
                          const float* __restrict__ ptra, float* __restrict__ mats) {
  int bn = threadIdx.x;
  if (bn >= NIMG) return;
  double pr[9], ik[9];
  for (int i = 0; i < 9; i++) { pr[i] = prot[bn*9 + i]; ik[i] = intr[bn*9 + i]; }
  double Minv[9], Kinv[9];
  inv3(pr, Minv);
  inv3(ik, Kinv);
  float* m = mats + bn*24;
  for (int i = 0; i < 9; i++) m[i] = (float)Minv[i];
  float kf[9];
  for (int i = 0; i < 9; i++) kf[i] = (float)Kinv[i];
  {
#pragma clang fp contract(off)
    for (int i = 0; i < 3; i++)
      for (int j = 0; j < 3; j++) {
        float s = rots[bn*9 + i*3 + 0] * kf[0*3 + j];
        s = s + rots[bn*9 + i*3 + 1] * kf[1*3 + j];
        s = s + rots[bn*9 + i*3 + 2] * kf[2*3 + j];
        m[9 + i*3 + j] = s;
      }
  }
  m[18] = ptra[bn*3 + 0]; m[19] = ptra[bn*3 + 1]; m[20] = ptra[bn*3 + 2];
  m[21] = trans[bn*3 + 0]; m[22] = trans[bn*3 + 1]; m[23] = trans[bn*3 + 2];
}

// ---------------------------------------------------------------------------
// Kernel 2: feat = W_depth @ x, softmax over first 59 channels.
// ---------------------------------------------------------------------------
__global__ __launch_bounds__(256) void gemm_softmax(const float* __restrict__ x,
    const float* __restrict__ Wd, const float* __restrict__ bd,
    float* __restrict__ depth_ws, float* __restrict__ img_ws) {
  __shared__ float smem[64*68 + 64*132];
  __shared__ float sm[64], ss[64];
  float* Xt = smem;
  float* Wt = smem + 64*68;
  int t = threadIdx.x;
  int blk = blockIdx.x;
  int bn = blk / 11, tile = blk - bn*11;
  int pixbase = tile * 64;
  const float* xim = x + (size_t)bn * 512 * NPIX + pixbase;
  int pg = t & 15, og = t >> 4;
  int p0 = pg << 2, o0 = og << 3;
  float acc[8][4];
  for (int i = 0; i < 8; i++) for (int j = 0; j < 4; j++) acc[i][j] = 0.f;

  for (int kc = 0; kc < 512; kc += 64) {
    for (int i = 0; i < 16; i++) {
      int cl = (t >> 6) + (i << 2);
      Xt[cl*68 + (t & 63)] = xim[(size_t)(kc + cl) * NPIX + (t & 63)];
    }
    for (int i = 0; i < 32; i++) {
      int idx = t + (i << 8);
      int o = idx >> 6, k = idx & 63;
      Wt[k*132 + o] = (o < 123) ? Wd[o*512 + kc + k] : 0.f;
    }
    __syncthreads();
#pragma unroll 8
    for (int k = 0; k < 64; k++) {
      const float4 a  = *(const float4*)&Xt[k*68 + p0];
      const float4 w0 = *(const float4*)&Wt[k*132 + o0];
      const float4 w1 = *(const float4*)&Wt[k*132 + o0 + 4];
      float av[4] = {a.x, a.y, a.z, a.w};
      float wv[8] = {w0.x, w0.y, w0.z, w0.w, w1.x, w1.y, w1.z, w1.w};
      for (int oi = 0; oi < 8; oi++)
        for (int pi = 0; pi < 4; pi++)
          acc[oi][pi] += wv[oi] * av[pi];
    }
    __syncthreads();
  }

  float* F = smem;
  for (int oi = 0; oi < 8; oi++) {
    int o = o0 + oi;
    float b = (o < 123) ? bd[o] : 0.f;
    for (int pi = 0; pi < 4; pi++) F[o*68 + p0 + pi] = acc[oi][pi] + b;
  }
  __syncthreads();

  {
    int pix = t & 63;
    float mmax = -3.4e38f;
    for (int d = 0; d < DB; d++) mmax = fmaxf(mmax, F[d*68 + pix]);
    float s = 0.f;
    for (int d = 0; d < DB; d++) s += expf(F[d*68 + pix] - mmax);
    if (t < 64) { sm[t] = mmax; ss[t] = s; }
  }
  __syncthreads();

  {
    int c = t & 63;
    for (int p = t >> 6; p < 64; p += 4) {
      size_t rec = (size_t)(bn*NPIX + pixbase + p) * 64;
      if (c < DB) depth_ws[rec + c] = expf(F[c*68 + p] - sm[p]) / ss[p];
      img_ws[rec + c] = F[(DB + c)*68 + p];
    }
  }
}

// ---------------------------------------------------------------------------
// Kernel 3: geometry -> sliced key + rank via hist atomic.
// ---------------------------------------------------------------------------
__global__ __launch_bounds__(256) void geom_k(const float* __restrict__ mats,
    int2* __restrict__ pr, int* __restrict__ hist) {
  int wid = (blockIdx.x << 2) + (threadIdx.x >> 6);
  int lane = threadIdx.x & 63;
  int bn = wid / NPIX;
  int pix = wid - bn*NPIX;
  int b = bn / NCAM;
  int h = pix / 44, w = pix - h*44;
  const float* M = mats + bn*24;

  int code = -1;
  {
#pragma clang fp contract(off)
    float xs = (float)((double)w * (703.0 / 43.0));
    float ys = (float)(h * 17);
    float dval = (float)(lane + 1);
    float vx = xs - M[18], vy = ys - M[19], vz = dval - M[20];
    float qx = M[0]*vx + M[1]*vy + M[2]*vz;
    float qy = M[3]*vx + M[4]*vy + M[5]*vz;
    float qz = M[6]*vx + M[7]*vy + M[8]*vz;
    float rx = qx*qz, ry = qy*qz;
    float px = M[9]*rx  + M[10]*ry + M[11]*qz + M[21];
    float py = M[12]*rx + M[13]*ry + M[14]*qz + M[22];
    float pz = M[15]*rx + M[16]*ry + M[17]*qz + M[23];
    float gx = floorf((px - (-50.8f - 0.4f)) / 0.8f);
    float gy = floorf((py - (-50.8f - 0.4f)) / 0.8f);
    float gz = floorf((pz - (0.0f - 10.0f)) / 20.0f);
    bool kept = (lane < DB) && (gx >= 0.f) && (gx < 128.f) &&
                (gy >= 0.f) && (gy < 128.f) && (gz == 0.f);
    if (kept) code = (b << 14) + (int)gy * 128 + (int)gx;
  }

  if (lane < DB) {
    int key = -1, r = 0;
    if (code >= 0) {
      key = code * SLC + ((wid + lane) & (SLC - 1));
      r = atomicAdd(&hist[key], 1);
    }
    pr[(size_t)wid * DB + lane] = make_int2(key, r);
  }
}

// ---------------------------------------------------------------------------
// Kernels 4a/4b/4c: hierarchical exclusive scan of hist[NKEY].
// ---------------------------------------------------------------------------
__global__ __launch_bounds__(256) void scan1_k(const int* __restrict__ hist,
    int* __restrict__ blockSums) {
  __shared__ int red[256];
  int t = threadIdx.x;
  const int4* h4 = (const int4*)(hist + (blockIdx.x << 10));
  int4 v = h4[t];
  red[t] = v.x + v.y + v.z + v.w;
  __syncthreads();
  for (int ofs = 128; ofs > 0; ofs >>= 1) {
    if (t < ofs) red[t] += red[t + ofs];
    __syncthreads();
  }
  if (t == 0) blockSums[blockIdx.x] = red[0];
}

__global__ __launch_bounds__(512) void scan2_k(int* __restrict__ blockSums,
    int* __restrict__ totalK) {
  __shared__ int buf[2][512];
  int t = threadIdx.x;
  buf[0][t] = blockSums[t];
  __syncthreads();
  int src = 0;
  for (int ofs = 1; ofs < 512; ofs <<= 1) {
    int v = buf[src][t];
    if (t >= ofs) v += buf[src][t - ofs];
    buf[src ^ 1][t] = v;
    __syncthreads();
    src ^= 1;
  }
  blockSums[t] = (t == 0) ? 0 : buf[src][t - 1];
  if (t == 511) *totalK = buf[src][511];
}

__global__ __launch_bounds__(256) void scan3_k(int* __restrict__ hist,
    const int* __restrict__ blockSums) {
  __shared__ int buf[2][256];
  int t = threadIdx.x;
  int4* h4 = (int4*)(hist + (blockIdx.x << 10));
  int4 v = h4[t];
  int s = v.x + v.y + v.z + v.w;
  buf[0][t] = s;
  __syncthreads();
  int src = 0;
  for (int ofs = 1; ofs < 256; ofs <<= 1) {
    int vv = buf[src][t];
    if (t >= ofs) vv += buf[src][t - ofs];
    buf[src ^ 1][t] = vv;
    __syncthreads();
    src ^= 1;
  }
  int run = blockSums[blockIdx.x] + ((t == 0) ? 0 : buf[src][t - 1]);
  int4 o;
  o.x = run; run += v.x;
  o.y = run; run += v.y;
  o.z = run; run += v.z;
  o.w = run;
  h4[t] = o;
}

// ---------------------------------------------------------------------------
// Kernel 5: atomic-free placement: pos = offsets[key] + rank.
// ---------------------------------------------------------------------------
__global__ __launch_bounds__(256) void order_k(const int2* __restrict__ pr,
    const int* __restrict__ offsets, int2* __restrict__ sorted) {
  int p = blockIdx.x * 256 + threadIdx.x;
  if (p >= P_TOT) return;
  int2 e = pr[p];
  if (e.x >= 0) {
    int pos = offsets[e.x] + e.y;
    int bnpix = p / DB;
    int d = p - bnpix * DB;
    sorted[pos] = make_int2(e.x / SLC, (bnpix << 6) + d);
  }
}

// ---------------------------------------------------------------------------
// Kernel 6: segmented gather. One wave per CHUNK sorted points; lane = channel.
// ---------------------------------------------------------------------------
__global__ __launch_bounds__(256) void gather_seg(const int2* __restrict__ sorted,
    const int* __restrict__ totalK,
    const float* __restrict__ depth_ws, const float* __restrict__ img_ws,
    float* __restrict__ out) {
  int wid = (blockIdx.x << 2) + (threadIdx.x >> 6);
  int lane = threadIdx.x & 63;
  int K = *totalK;
  int start = wid * CHUNK;
  if (start >= K) return;
  int end = min(start + CHUNK, K);

  int2 s0 = sorted[start];
  int cur = s0.x;
  float acc = 0.f;
  for (int i = start; i < end; ++i) {
    int2 s = sorted[i];
    if (s.x != cur) {                     // wave-uniform branch
      int b = cur >> 14, vox = cur & 16383;
      unsafeAtomicAdd(&out[((size_t)((b << 6) + lane) << 14) + vox], acc);
      acc = 0.f;
      cur = s.x;
    }
    float dep = depth_ws[s.y];                          // broadcast load
    float im  = img_ws[(s.y & 0x7FFFFFC0) + lane];      // coalesced 256B
    acc += dep * im;
  }
  int b = cur >> 14, vox = cur & 16383;
  unsafeAtomicAdd(&out[((size_t)((b << 6) + lane) << 14) + vox], acc);
}

// ---------------------------------------------------------------------------
extern "C" void kernel_launch(void* const* d_in, const int* in_sizes, int n_in,
                              void* d_out, int out_size, void* d_ws, size_t ws_size,
                              hipStream_t stream) {
  const float* x    = (const float*)d_in[0];
  const float* rots = (const float*)d_in[1];
  const float* trn  = (const float*)d_in[2];
  const float* intr = (const float*)d_in[3];
  const float* prot = (const float*)d_in[4];
  const float* ptra = (const float*)d_in[5];
  const float* Wd   = (const float*)d_in[6];
  const float* bd   = (const float*)d_in[7];
  float* out = (float*)d_out;
  float* ws  = (float*)d_ws;

  float* mats     = ws;                                    // 1024 floats
  float* depth_ws = ws + 1024;                             // 1,081,344
  float* img_ws   = depth_ws + (size_t)NIMG*NPIX*64;       // 1,081,344
  int*   hist     = (int*)(img_ws + (size_t)NIMG*NPIX*64); // 524,288 (16B-aligned)
  int*   blockSums= hist + NKEY;                           // 512
  int*   totalK   = blockSums + 512;                       // 4 (pad)
  int2*  pr       = (int2*)(totalK + 4);                   // 996,864 int2
  int2*  sorted   = pr + P_TOT;                            // 996,864 int2

  (void)hipMemsetAsync(hist, 0, NKEY * sizeof(int), stream);
  (void)hipMemsetAsync(d_out, 0, (size_t)out_size * sizeof(float), stream);
  prep_mats<<<1, 32, 0, stream>>>(rots, trn, intr, prot, ptra, mats);
  gemm_softmax<<<NIMG*11, 256, 0, stream>>>(x, Wd, bd, depth_ws, img_ws);
  geom_k<<<NIMG*NPIX/4, 256, 0, stream>>>(mats, pr, hist);
  scan1_k<<<SCAN_BLKS, 256, 0, stream>>>(hist, blockSums);
  scan2_k<<<1, 512, 0, stream>>>(blockSums, totalK);
  scan3_k<<<SCAN_BLKS, 256, 0, stream>>>(hist, blockSums);
  order_k<<<(P_TOT + 255)/256, 256, 0, stream>>>(pr, hist, sorted);
  gather_seg<<<(P_TOT/CHUNK + 3)/4, 256, 0, stream>>>(sorted, totalK, depth_ws, img_ws, out);
}

// Round 8
// 151.544 us; speedup vs baseline: 7.1232x; 1.1441x over previous
//
#include <hip/hip_runtime.h>

#define NPIX 704
#define NIMG 24
#define NB 4
#define NCAM 6
#define DB 59
#define CT 64
#define P_TOT (NIMG*NPIX*DB)   // 996864
#define NVOX 65536             // 4 batches * 128*128 (gz==0 only)
#define SLC 8                  // histogram slices (contention spreading)
#define NKEY (NVOX*SLC)        // 524288
#define CHUNK 64
#define SCAN_BLKS 512          // NKEY / 1024
#define MPIX (NIMG*NPIX)       // 16896

// ---------------------------------------------------------------------------
// Kernel 1: per-(b,n) matrix prep.
// ---------------------------------------------------------------------------
__device__ inline void inv3(const double a[9], double o[9]) {
  double c0 = a[4]*a[8] - a[5]*a[7];
  double c1 = a[3]*a[8] - a[5]*a[6];
  double c2 = a[3]*a[7] - a[4]*a[6];
  double det = a[0]*c0 - a[1]*c1 + a[2]*c2;
  double id = 1.0 / det;
  o[0] =  c0 * id;
  o[1] = (a[2]*a[7] - a[1]*a[8]) * id;
  o[2] = (a[1]*a[5] - a[2]*a[4]) * id;
  o[3] = -c1 * id;
  o[4] = (a[0]*a[8] - a[2]*a[6]) * id;
  o[5] = (a[2]*a[3] - a[0]*a[5]) * id;
  o[6] =  c2 * id;
  o[7] = (a[1]*a[6] - a[0]*a[7]) * id;
  o[8] = (a[0]*a[4] - a[1]*a[3]) * id;
}

__global__ void prep_mats(const float* __restrict__ rots, const float* __restrict__ trans,
                          const float* __restrict__ intr, const float* __restrict__ prot,
                          const float* __restrict__ ptra, float* __restrict__ mats) {
  int bn = threadIdx.x;
  if (bn >= NIMG) return;
  double pr[9], ik[9];
  for (int i = 0; i < 9; i++) { pr[i] = prot[bn*9 + i]; ik[i] = intr[bn*9 + i]; }
  double Minv[9], Kinv[9];
  inv3(pr, Minv);
  inv3(ik, Kinv);
  float* m = mats + bn*24;
  for (int i = 0; i < 9; i++) m[i] = (float)Minv[i];
  float kf[9];
  for (int i = 0; i < 9; i++) kf[i] = (float)Kinv[i];
  {
#pragma clang fp contract(off)
    for (int i = 0; i < 3; i++)
      for (int j = 0; j < 3; j++) {
        float s = rots[bn*9 + i*3 + 0] * kf[0*3 + j];
        s = s + rots[bn*9 + i*3 + 1] * kf[1*3 + j];
        s = s + rots[bn*9 + i*3 + 2] * kf[2*3 + j];
        m[9 + i*3 + j] = s;
      }
  }
  m[18] = ptra[bn*3 + 0]; m[19] = ptra[bn*3 + 1]; m[20] = ptra[bn*3 + 2];
  m[21] = trans[bn*3 + 0]; m[22] = trans[bn*3 + 1]; m[23] = trans[bn*3 + 2];
}

// ---------------------------------------------------------------------------
// Kernel 2a: transpose W to k-major, zero-padded: Wt_g[k][o], o in [0,128).
// ---------------------------------------------------------------------------
__global__ __launch_bounds__(256) void transpose_w(const float* __restrict__ Wd,
    float* __restrict__ Wt_g) {
  int idx = blockIdx.x * 256 + threadIdx.x;   // 128*512 entries
  int o = idx >> 9, k = idx & 511;
  Wt_g[k * 128 + o] = (o < 123) ? Wd[o * 512 + k] : 0.f;
}

// ---------------------------------------------------------------------------
// Kernel 2b: partial GEMM. Tile: 64 pix x 64 outs x 256 K. Grid 264*4.
// feat_part[ks][pix][128] — conflict-free LDS, coalesced loads.
// ---------------------------------------------------------------------------
__global__ __launch_bounds__(256) void gemm_part(const float* __restrict__ x,
    const float* __restrict__ Wt_g, float* __restrict__ feat_part) {
  __shared__ float Xt[64][68];
  __shared__ float Wt[64][68];
  int t = threadIdx.x;
  int blk = blockIdx.x;
  int mt = blk >> 2;
  int nt = blk & 1;
  int ks = (blk >> 1) & 1;
  int pixbase = mt * 64;                 // 704 = 11*64: tile stays in one image
  int obase = nt * 64;
  int kbase = ks * 256;
  int bn = pixbase / NPIX;
  int pix0 = pixbase - bn * NPIX;
  const float* xb = x + (size_t)bn * 512 * NPIX + pix0;

  int pg = t & 15, og = t >> 4;
  int p0 = pg << 2, o0 = og << 2;
  float acc[4][4];
  for (int i = 0; i < 4; i++) for (int j = 0; j < 4; j++) acc[i][j] = 0.f;

  for (int kc = 0; kc < 256; kc += 64) {
    int lane = t & 63, quad = t >> 6;
    for (int i = 0; i < 16; i++) {
      int cl = quad + (i << 2);
      int kk = kbase + kc + cl;
      Xt[cl][lane] = xb[(size_t)kk * NPIX + lane];
      Wt[cl][lane] = Wt_g[kk * 128 + obase + lane];
    }
    __syncthreads();
#pragma unroll 8
    for (int k = 0; k < 64; k++) {
      const float4 a = *(const float4*)&Xt[k][p0];
      const float4 w = *(const float4*)&Wt[k][o0];
      float av[4] = {a.x, a.y, a.z, a.w};
      float wv[4] = {w.x, w.y, w.z, w.w};
      for (int oi = 0; oi < 4; oi++)
        for (int pi = 0; pi < 4; pi++)
          acc[oi][pi] += wv[oi] * av[pi];
    }
    __syncthreads();
  }

  float* fp = feat_part + ((size_t)ks * MPIX + pixbase) * 128 + obase;
  for (int pi = 0; pi < 4; pi++) {
    float4 v;
    v.x = acc[0][pi]; v.y = acc[1][pi]; v.z = acc[2][pi]; v.w = acc[3][pi];
    *(float4*)&fp[(size_t)(p0 + pi) * 128 + o0] = v;
  }
}

// ---------------------------------------------------------------------------
// Kernel 2c: reduce K-partials + bias, wave softmax, write depth/img.
// One wave per pixel, lane = channel.
// ---------------------------------------------------------------------------
__global__ __launch_bounds__(256) void reduce_softmax(const float* __restrict__ feat_part,
    const float* __restrict__ bd,
    float* __restrict__ depth_ws, float* __restrict__ img_ws) {
  int pixg = (blockIdx.x << 2) + (threadIdx.x >> 6);   // 0..16895
  int c = threadIdx.x & 63;
  const float* f0 = feat_part + (size_t)pixg * 128;
  const float* f1 = feat_part + ((size_t)MPIX + pixg) * 128;
  float fA = f0[c] + f1[c] + bd[c];                     // channels 0..63
  float fI = f0[DB + c] + f1[DB + c] + bd[DB + c];      // channels 59..122

  // softmax over channels 0..58 (fA lanes 0..58)
  float mv = (c < DB) ? fA : -3.4e38f;
  for (int ofs = 32; ofs > 0; ofs >>= 1) mv = fmaxf(mv, __shfl_xor(mv, ofs));
  float ev = (c < DB) ? expf(fA - mv) : 0.f;
  float sv = ev;
  for (int ofs = 32; ofs > 0; ofs >>= 1) sv += __shfl_xor(sv, ofs);

  size_t rec = (size_t)pixg * 64;
  if (c < DB) depth_ws[rec + c] = ev / sv;
  img_ws[rec + c] = fI;
}

// ---------------------------------------------------------------------------
// Kernel 3: geometry -> sliced key + rank via hist atomic.
// ---------------------------------------------------------------------------
__global__ __launch_bounds__(256) void geom_k(const float* __restrict__ mats,
    int2* __restrict__ pr, int* __restrict__ hist) {
  int wid = (blockIdx.x << 2) + (threadIdx.x >> 6);
  int lane = threadIdx.x & 63;
  int bn = wid / NPIX;
  int pix = wid - bn*NPIX;
  int b = bn / NCAM;
  int h = pix / 44, w = pix - h*44;
  const float* M = mats + bn*24;

  int code = -1;
  {
#pragma clang fp contract(off)
    float xs = (float)((double)w * (703.0 / 43.0));
    float ys = (float)(h * 17);
    float dval = (float)(lane + 1);
    float vx = xs - M[18], vy = ys - M[19], vz = dval - M[20];
    float qx = M[0]*vx + M[1]*vy + M[2]*vz;
    float qy = M[3]*vx + M[4]*vy + M[5]*vz;
    float qz = M[6]*vx + M[7]*vy + M[8]*vz;
    float rx = qx*qz, ry = qy*qz;
    float px = M[9]*rx  + M[10]*ry + M[11]*qz + M[21];
    float py = M[12]*rx + M[13]*ry + M[14]*qz + M[22];
    float pz = M[15]*rx + M[16]*ry + M[17]*qz + M[23];
    float gx = floorf((px - (-50.8f - 0.4f)) / 0.8f);
    float gy = floorf((py - (-50.8f - 0.4f)) / 0.8f);
    float gz = floorf((pz - (0.0f - 10.0f)) / 20.0f);
    bool kept = (lane < DB) && (gx >= 0.f) && (gx < 128.f) &&
                (gy >= 0.f) && (gy < 128.f) && (gz == 0.f);
    if (kept) code = (b << 14) + (int)gy * 128 + (int)gx;
  }

  if (lane < DB) {
    int key = -1, r = 0;
    if (code >= 0) {
      key = code * SLC + ((wid + lane) & (SLC - 1));
      r = atomicAdd(&hist[key], 1);
    }
    pr[(size_t)wid * DB + lane] = make_int2(key, r);
  }
}

// ---------------------------------------------------------------------------
// Kernels 4a/4b/4c: hierarchical exclusive scan of hist[NKEY].
// ---------------------------------------------------------------------------
__global__ __launch_bounds__(256) void scan1_k(const int* __restrict__ hist,
    int* __restrict__ blockSums) {
  __shared__ int red[256];
  int t = threadIdx.x;
  const int4* h4 = (const int4*)(hist + (blockIdx.x << 10));
  int4 v = h4[t];
  red[t] = v.x + v.y + v.z + v.w;
  __syncthreads();
  for (int ofs = 128; ofs > 0; ofs >>= 1) {
    if (t < ofs) red[t] += red[t + ofs];
    __syncthreads();
  }
  if (t == 0) blockSums[blockIdx.x] = red[0];
}

__global__ __launch_bounds__(512) void scan2_k(int* __restrict__ blockSums,
    int* __restrict__ totalK) {
  __shared__ int buf[2][512];
  int t = threadIdx.x;
  buf[0][t] = blockSums[t];
  __syncthreads();
  int src = 0;
  for (int ofs = 1; ofs < 512; ofs <<= 1) {
    int v = buf[src][t];
    if (t >= ofs) v += buf[src][t - ofs];
    buf[src ^ 1][t] = v;
    __syncthreads();
    src ^= 1;
  }
  blockSums[t] = (t == 0) ? 0 : buf[src][t - 1];
  if (t == 511) *totalK = buf[src][511];
}

__global__ __launch_bounds__(256) void scan3_k(int* __restrict__ hist,
    const int* __restrict__ blockSums) {
  __shared__ int buf[2][256];
  int t = threadIdx.x;
  int4* h4 = (int4*)(hist + (blockIdx.x << 10));
  int4 v = h4[t];
  int s = v.x + v.y + v.z + v.w;
  buf[0][t] = s;
  __syncthreads();
  int src = 0;
  for (int ofs = 1; ofs < 256; ofs <<= 1) {
    int vv = buf[src][t];
    if (t >= ofs) vv += buf[src][t - ofs];
    buf[src ^ 1][t] = vv;
    __syncthreads();
    src ^= 1;
  }
  int run = blockSums[blockIdx.x] + ((t == 0) ? 0 : buf[src][t - 1]);
  int4 o;
  o.x = run; run += v.x;
  o.y = run; run += v.y;
  o.z = run; run += v.z;
  o.w = run;
  h4[t] = o;
}

// ---------------------------------------------------------------------------
// Kernel 5: atomic-free placement: pos = offsets[key] + rank.
// ---------------------------------------------------------------------------
__global__ __launch_bounds__(256) void order_k(const int2* __restrict__ pr,
    const int* __restrict__ offsets, int2* __restrict__ sorted) {
  int p = blockIdx.x * 256 + threadIdx.x;
  if (p >= P_TOT) return;
  int2 e = pr[p];
  if (e.x >= 0) {
    int pos = offsets[e.x] + e.y;
    int bnpix = p / DB;
    int d = p - bnpix * DB;
    sorted[pos] = make_int2(e.x / SLC, (bnpix << 6) + d);
  }
}

// ---------------------------------------------------------------------------
// Kernel 6: segmented gather. One wave per CHUNK sorted points; lane = channel.
// ---------------------------------------------------------------------------
__global__ __launch_bounds__(256) void gather_seg(const int2* __restrict__ sorted,
    const int* __restrict__ totalK,
    const float* __restrict__ depth_ws, const float* __restrict__ img_ws,
    float* __restrict__ out) {
  int wid = (blockIdx.x << 2) + (threadIdx.x >> 6);
  int lane = threadIdx.x & 63;
  int K = *totalK;
  int start = wid * CHUNK;
  if (start >= K) return;
  int end = min(start + CHUNK, K);

  int2 s0 = sorted[start];
  int cur = s0.x;
  float acc = 0.f;
  for (int i = start; i < end; ++i) {
    int2 s = sorted[i];
    if (s.x != cur) {                     // wave-uniform branch
      int b = cur >> 14, vox = cur & 16383;
      unsafeAtomicAdd(&out[((size_t)((b << 6) + lane) << 14) + vox], acc);
      acc = 0.f;
      cur = s.x;
    }
    float dep = depth_ws[s.y];                          // broadcast load
    float im  = img_ws[(s.y & 0x7FFFFFC0) + lane];      // coalesced 256B
    acc += dep * im;
  }
  int b = cur >> 14, vox = cur & 16383;
  unsafeAtomicAdd(&out[((size_t)((b << 6) + lane) << 14) + vox], acc);
}

// ---------------------------------------------------------------------------
extern "C" void kernel_launch(void* const* d_in, const int* in_sizes, int n_in,
                              void* d_out, int out_size, void* d_ws, size_t ws_size,
                              hipStream_t stream) {
  const float* x    = (const float*)d_in[0];
  const float* rots = (const float*)d_in[1];
  const float* trn  = (const float*)d_in[2];
  const float* intr = (const float*)d_in[3];
  const float* prot = (const float*)d_in[4];
  const float* ptra = (const float*)d_in[5];
  const float* Wd   = (const float*)d_in[6];
  const float* bd   = (const float*)d_in[7];
  float* out = (float*)d_out;
  float* ws  = (float*)d_ws;

  // Layout identical in extent to the validated round-6 footprint.
  float* mats     = ws;                                    // 1024 floats
  float* depth_ws = ws + 1024;                             // 1,081,344
  float* img_ws   = depth_ws + (size_t)MPIX*64;            // 1,081,344
  int*   hist     = (int*)(img_ws + (size_t)MPIX*64);      // 524,288 (16B-aligned)
  int*   blockSums= hist + NKEY;                           // 512
  int*   totalK   = blockSums + 512;                       // 4 (pad)
  int2*  pr       = (int2*)(totalK + 4);                   // 996,864 int2
  int2*  sorted   = pr + P_TOT;                            // 996,864 int2
  // Wt_g aliases the head of depth_ws: only gemm_part reads it, and depth_ws
  // is first written by reduce_softmax (after gemm_part completes).
  float* Wt_g     = depth_ws;                              // 65,536 floats
  // feat_part aliases hist..sorted (17.3 MB <= 18.0 MB); dead after reduce.
  float* feat_part= (float*)hist;

  prep_mats<<<1, 32, 0, stream>>>(rots, trn, intr, prot, ptra, mats);
  transpose_w<<<256, 256, 0, stream>>>(Wd, Wt_g);
  gemm_part<<<264*4, 256, 0, stream>>>(x, Wt_g, feat_part);
  reduce_softmax<<<MPIX/4, 256, 0, stream>>>(feat_part, bd, depth_ws, img_ws);
  (void)hipMemsetAsync(hist, 0, NKEY * sizeof(int), stream);
  (void)hipMemsetAsync(d_out, 0, (size_t)out_size * sizeof(float), stream);
  geom_k<<<NIMG*NPIX/4, 256, 0, stream>>>(mats, pr, hist);
  scan1_k<<<SCAN_BLKS, 256, 0, stream>>>(hist, blockSums);
  scan2_k<<<1, 512, 0, stream>>>(blockSums, totalK);
  scan3_k<<<SCAN_BLKS, 256, 0, stream>>>(hist, blockSums);
  order_k<<<(P_TOT + 255)/256, 256, 0, stream>>>(pr, hist, sorted);
  gather_seg<<<(P_TOT/CHUNK + 3)/4, 256, 0, stream>>>(sorted, totalK, depth_ws, img_ws, out);
}

// Round 9
// 149.260 us; speedup vs baseline: 7.2322x; 1.0153x over previous
//
#include <hip/hip_runtime.h>

#define NPIX 704
#define NIMG 24
#define NB 4
#define NCAM 6
#define DB 59
#define CT 64
#define P_TOT (NIMG*NPIX*DB)   // 996864
#define NVOX 65536             // 4 batches * 128*128 (gz==0 only)
#define SLC 8                  // histogram slices (contention spreading)
#define NKEY (NVOX*SLC)        // 524288
#define CHUNK 64
#define SCAN_BLKS 512          // NKEY / 1024
#define MPIX (NIMG*NPIX)       // 16896

// ---------------------------------------------------------------------------
// Kernel 1: W transpose (blocks 0..255) + per-(b,n) matrix prep (block 256).
// ---------------------------------------------------------------------------
__device__ inline void inv3(const double a[9], double o[9]) {
  double c0 = a[4]*a[8] - a[5]*a[7];
  double c1 = a[3]*a[8] - a[5]*a[6];
  double c2 = a[3]*a[7] - a[4]*a[6];
  double det = a[0]*c0 - a[1]*c1 + a[2]*c2;
  double id = 1.0 / det;
  o[0] =  c0 * id;
  o[1] = (a[2]*a[7] - a[1]*a[8]) * id;
  o[2] = (a[1]*a[5] - a[2]*a[4]) * id;
  o[3] = -c1 * id;
  o[4] = (a[0]*a[8] - a[2]*a[6]) * id;
  o[5] = (a[2]*a[3] - a[0]*a[5]) * id;
  o[6] =  c2 * id;
  o[7] = (a[1]*a[6] - a[0]*a[7]) * id;
  o[8] = (a[0]*a[4] - a[1]*a[3]) * id;
}

__global__ __launch_bounds__(256) void prep_transpose(
    const float* __restrict__ rots, const float* __restrict__ trans,
    const float* __restrict__ intr, const float* __restrict__ prot,
    const float* __restrict__ ptra, float* __restrict__ mats,
    const float* __restrict__ Wd, float* __restrict__ Wt_g) {
  if (blockIdx.x < 256) {
    int idx = blockIdx.x * 256 + threadIdx.x;   // 128*512 entries
    int o = idx >> 9, k = idx & 511;
    Wt_g[k * 128 + o] = (o < 123) ? Wd[o * 512 + k] : 0.f;
    return;
  }
  int bn = threadIdx.x;
  if (bn >= NIMG) return;
  double pr[9], ik[9];
  for (int i = 0; i < 9; i++) { pr[i] = prot[bn*9 + i]; ik[i] = intr[bn*9 + i]; }
  double Minv[9], Kinv[9];
  inv3(pr, Minv);
  inv3(ik, Kinv);
  float* m = mats + bn*24;
  for (int i = 0; i < 9; i++) m[i] = (float)Minv[i];
  float kf[9];
  for (int i = 0; i < 9; i++) kf[i] = (float)Kinv[i];
  {
#pragma clang fp contract(off)
    for (int i = 0; i < 3; i++)
      for (int j = 0; j < 3; j++) {
        float s = rots[bn*9 + i*3 + 0] * kf[0*3 + j];
        s = s + rots[bn*9 + i*3 + 1] * kf[1*3 + j];
        s = s + rots[bn*9 + i*3 + 2] * kf[2*3 + j];
        m[9 + i*3 + j] = s;
      }
  }
  m[18] = ptra[bn*3 + 0]; m[19] = ptra[bn*3 + 1]; m[20] = ptra[bn*3 + 2];
  m[21] = trans[bn*3 + 0]; m[22] = trans[bn*3 + 1]; m[23] = trans[bn*3 + 2];
}

// ---------------------------------------------------------------------------
// Kernel 2b: partial GEMM. Tile: 32 pix x 128 outs x 256 K. Grid 528*2,
// 128 threads. acc = 4 pix x (4 + 4) outs. feat_part[ks][pix][128].
// ---------------------------------------------------------------------------
__global__ __launch_bounds__(128) void gemm_part(const float* __restrict__ x,
    const float* __restrict__ Wt_g, float* __restrict__ feat_part) {
  __shared__ float Xt[32][36];
  __shared__ float Wt[32][132];
  int t = threadIdx.x;
  int blk = blockIdx.x;
  int mt = blk >> 1;
  int ks = blk & 1;
  int pixbase = mt * 32;                 // 704 = 22*32: tile stays in one image
  int kbase = ks * 256;
  int bn = pixbase / NPIX;
  int pix0 = pixbase - bn * NPIX;
  const float* xb = x + (size_t)bn * 512 * NPIX + pix0;

  int og = t & 15, pg = t >> 4;
  int o0 = og << 2, p0 = pg << 2;
  float acc[8][4];
  for (int i = 0; i < 8; i++) for (int j = 0; j < 4; j++) acc[i][j] = 0.f;

  for (int kc = 0; kc < 256; kc += 32) {
    // stage X: 32k x 32pix
#pragma unroll
    for (int i = 0; i < 8; i++) {
      int idx = t + (i << 7);
      int k = idx >> 5, p = idx & 31;
      Xt[k][p] = xb[(size_t)(kbase + kc + k) * NPIX + p];
    }
    // stage W: 32k x 128o (float4)
#pragma unroll
    for (int i = 0; i < 8; i++) {
      int idx = t + (i << 7);
      int k = idx >> 5, o4 = (idx & 31) << 2;
      *(float4*)&Wt[k][o4] = *(const float4*)&Wt_g[(size_t)(kbase + kc + k) * 128 + o4];
    }
    __syncthreads();
#pragma unroll 4
    for (int k = 0; k < 32; k++) {
      const float4 a  = *(const float4*)&Xt[k][p0];
      const float4 w0 = *(const float4*)&Wt[k][o0];
      const float4 w1 = *(const float4*)&Wt[k][o0 + 64];
      float av[4] = {a.x, a.y, a.z, a.w};
      float wv[8] = {w0.x, w0.y, w0.z, w0.w, w1.x, w1.y, w1.z, w1.w};
      for (int oi = 0; oi < 8; oi++)
        for (int pi = 0; pi < 4; pi++)
          acc[oi][pi] += wv[oi] * av[pi];
    }
    __syncthreads();
  }

  float* fp = feat_part + ((size_t)ks * MPIX + pixbase) * 128;
  for (int pi = 0; pi < 4; pi++) {
    int row = p0 + pi;
    float4 v0, v1;
    v0.x = acc[0][pi]; v0.y = acc[1][pi]; v0.z = acc[2][pi]; v0.w = acc[3][pi];
    v1.x = acc[4][pi]; v1.y = acc[5][pi]; v1.z = acc[6][pi]; v1.w = acc[7][pi];
    *(float4*)&fp[(size_t)row * 128 + o0] = v0;
    *(float4*)&fp[(size_t)row * 128 + o0 + 64] = v1;
  }
}

// ---------------------------------------------------------------------------
// Kernel 2c: reduce K-partials + bias, wave softmax, write depth/img.
// One wave per pixel, lane = channel.
// ---------------------------------------------------------------------------
__global__ __launch_bounds__(256) void reduce_softmax(const float* __restrict__ feat_part,
    const float* __restrict__ bd,
    float* __restrict__ depth_ws, float* __restrict__ img_ws) {
  int pixg = (blockIdx.x << 2) + (threadIdx.x >> 6);   // 0..16895
  int c = threadIdx.x & 63;
  const float* f0 = feat_part + (size_t)pixg * 128;
  const float* f1 = feat_part + ((size_t)MPIX + pixg) * 128;
  float fA = f0[c] + f1[c] + bd[c];                     // channels 0..63
  float fI = f0[DB + c] + f1[DB + c] + bd[DB + c];      // channels 59..122

  // softmax over channels 0..58 (fA lanes 0..58)
  float mv = (c < DB) ? fA : -3.4e38f;
  for (int ofs = 32; ofs > 0; ofs >>= 1) mv = fmaxf(mv, __shfl_xor(mv, ofs));
  float ev = (c < DB) ? expf(fA - mv) : 0.f;
  float sv = ev;
  for (int ofs = 32; ofs > 0; ofs >>= 1) sv += __shfl_xor(sv, ofs);

  size_t rec = (size_t)pixg * 64;
  if (c < DB) depth_ws[rec + c] = ev / sv;
  img_ws[rec + c] = fI;
}

// ---------------------------------------------------------------------------
// Kernel 3: geometry -> sliced key + rank via hist atomic.
// ---------------------------------------------------------------------------
__global__ __launch_bounds__(256) void geom_k(const float* __restrict__ mats,
    int2* __restrict__ pr, int* __restrict__ hist) {
  int wid = (blockIdx.x << 2) + (threadIdx.x >> 6);
  int lane = threadIdx.x & 63;
  int bn = wid / NPIX;
  int pix = wid - bn*NPIX;
  int b = bn / NCAM;
  int h = pix / 44, w = pix - h*44;
  const float* M = mats + bn*24;

  int code = -1;
  {
#pragma clang fp contract(off)
    float xs = (float)((double)w * (703.0 / 43.0));
    float ys = (float)(h * 17);
    float dval = (float)(lane + 1);
    float vx = xs - M[18], vy = ys - M[19], vz = dval - M[20];
    float qx = M[0]*vx + M[1]*vy + M[2]*vz;
    float qy = M[3]*vx + M[4]*vy + M[5]*vz;
    float qz = M[6]*vx + M[7]*vy + M[8]*vz;
    float rx = qx*qz, ry = qy*qz;
    float px = M[9]*rx  + M[10]*ry + M[11]*qz + M[21];
    float py = M[12]*rx + M[13]*ry + M[14]*qz + M[22];
    float pz = M[15]*rx + M[16]*ry + M[17]*qz + M[23];
    float gx = floorf((px - (-50.8f - 0.4f)) / 0.8f);
    float gy = floorf((py - (-50.8f - 0.4f)) / 0.8f);
    float gz = floorf((pz - (0.0f - 10.0f)) / 20.0f);
    bool kept = (lane < DB) && (gx >= 0.f) && (gx < 128.f) &&
                (gy >= 0.f) && (gy < 128.f) && (gz == 0.f);
    if (kept) code = (b << 14) + (int)gy * 128 + (int)gx;
  }

  if (lane < DB) {
    int key = -1, r = 0;
    if (code >= 0) {
      key = code * SLC + ((wid + lane) & (SLC - 1));
      r = atomicAdd(&hist[key], 1);
    }
    pr[(size_t)wid * DB + lane] = make_int2(key, r);
  }
}

// ---------------------------------------------------------------------------
// Kernels 4a/4b/4c: hierarchical exclusive scan of hist[NKEY].
// ---------------------------------------------------------------------------
__global__ __launch_bounds__(256) void scan1_k(const int* __restrict__ hist,
    int* __restrict__ blockSums) {
  __shared__ int red[256];
  int t = threadIdx.x;
  const int4* h4 = (const int4*)(hist + (blockIdx.x << 10));
  int4 v = h4[t];
  red[t] = v.x + v.y + v.z + v.w;
  __syncthreads();
  for (int ofs = 128; ofs > 0; ofs >>= 1) {
    if (t < ofs) red[t] += red[t + ofs];
    __syncthreads();
  }
  if (t == 0) blockSums[blockIdx.x] = red[0];
}

__global__ __launch_bounds__(512) void scan2_k(int* __restrict__ blockSums,
    int* __restrict__ totalK) {
  __shared__ int buf[2][512];
  int t = threadIdx.x;
  buf[0][t] = blockSums[t];
  __syncthreads();
  int src = 0;
  for (int ofs = 1; ofs < 512; ofs <<= 1) {
    int v = buf[src][t];
    if (t >= ofs) v += buf[src][t - ofs];
    buf[src ^ 1][t] = v;
    __syncthreads();
    src ^= 1;
  }
  blockSums[t] = (t == 0) ? 0 : buf[src][t - 1];
  if (t == 511) *totalK = buf[src][511];
}

__global__ __launch_bounds__(256) void scan3_k(int* __restrict__ hist,
    const int* __restrict__ blockSums) {
  __shared__ int buf[2][256];
  int t = threadIdx.x;
  int4* h4 = (int4*)(hist + (blockIdx.x << 10));
  int4 v = h4[t];
  int s = v.x + v.y + v.z + v.w;
  buf[0][t] = s;
  __syncthreads();
  int src = 0;
  for (int ofs = 1; ofs < 256; ofs <<= 1) {
    int vv = buf[src][t];
    if (t >= ofs) vv += buf[src][t - ofs];
    buf[src ^ 1][t] = vv;
    __syncthreads();
    src ^= 1;
  }
  int run = blockSums[blockIdx.x] + ((t == 0) ? 0 : buf[src][t - 1]);
  int4 o;
  o.x = run; run += v.x;
  o.y = run; run += v.y;
  o.z = run; run += v.z;
  o.w = run;
  h4[t] = o;
}

// ---------------------------------------------------------------------------
// Kernel 5: atomic-free placement: pos = offsets[key] + rank.
// ---------------------------------------------------------------------------
__global__ __launch_bounds__(256) void order_k(const int2* __restrict__ pr,
    const int* __restrict__ offsets, int2* __restrict__ sorted) {
  int p = blockIdx.x * 256 + threadIdx.x;
  if (p >= P_TOT) return;
  int2 e = pr[p];
  if (e.x >= 0) {
    int pos = offsets[e.x] + e.y;
    int bnpix = p / DB;
    int d = p - bnpix * DB;
    sorted[pos] = make_int2(e.x / SLC, (bnpix << 6) + d);
  }
}

// ---------------------------------------------------------------------------
// Kernel 6: segmented gather. One wave per CHUNK sorted points; lane = channel.
// ---------------------------------------------------------------------------
__global__ __launch_bounds__(256) void gather_seg(const int2* __restrict__ sorted,
    const int* __restrict__ totalK,
    const float* __restrict__ depth_ws, const float* __restrict__ img_ws,
    float* __restrict__ out) {
  int wid = (blockIdx.x << 2) + (threadIdx.x >> 6);
  int lane = threadIdx.x & 63;
  int K = *totalK;
  int start = wid * CHUNK;
  if (start >= K) return;
  int end = min(start + CHUNK, K);

  int2 s0 = sorted[start];
  int cur = s0.x;
  float acc = 0.f;
  for (int i = start; i < end; ++i) {
    int2 s = sorted[i];
    if (s.x != cur) {                     // wave-uniform branch
      int b = cur >> 14, vox = cur & 16383;
      unsafeAtomicAdd(&out[((size_t)((b << 6) + lane) << 14) + vox], acc);
      acc = 0.f;
      cur = s.x;
    }
    float dep = depth_ws[s.y];                          // broadcast load
    float im  = img_ws[(s.y & 0x7FFFFFC0) + lane];      // coalesced 256B
    acc += dep * im;
  }
  int b = cur >> 14, vox = cur & 16383;
  unsafeAtomicAdd(&out[((size_t)((b << 6) + lane) << 14) + vox], acc);
}

// ---------------------------------------------------------------------------
extern "C" void kernel_launch(void* const* d_in, const int* in_sizes, int n_in,
                              void* d_out, int out_size, void* d_ws, size_t ws_size,
                              hipStream_t stream) {
  const float* x    = (const float*)d_in[0];
  const float* rots = (const float*)d_in[1];
  const float* trn  = (const float*)d_in[2];
  const float* intr = (const float*)d_in[3];
  const float* prot = (const float*)d_in[4];
  const float* ptra = (const float*)d_in[5];
  const float* Wd   = (const float*)d_in[6];
  const float* bd   = (const float*)d_in[7];
  float* out = (float*)d_out;
  float* ws  = (float*)d_ws;

  // Layout identical in extent to the validated round-6/8 footprint.
  float* mats     = ws;                                    // 1024 floats
  float* depth_ws = ws + 1024;                             // 1,081,344
  float* img_ws   = depth_ws + (size_t)MPIX*64;            // 1,081,344
  int*   hist     = (int*)(img_ws + (size_t)MPIX*64);      // 524,288 (16B-aligned)
  int*   blockSums= hist + NKEY;                           // 512
  int*   totalK   = blockSums + 512;                       // 4 (pad)
  int2*  pr       = (int2*)(totalK + 4);                   // 996,864 int2
  int2*  sorted   = pr + P_TOT;                            // 996,864 int2
  // Wt_g aliases the head of depth_ws (read only by gemm_part, which
  // completes before reduce_softmax first writes depth_ws).
  float* Wt_g     = depth_ws;                              // 65,536 floats
  // feat_part aliases hist..sorted (17.3 MB <= 18.0 MB); dead after reduce.
  float* feat_part= (float*)hist;

  prep_transpose<<<257, 256, 0, stream>>>(rots, trn, intr, prot, ptra, mats, Wd, Wt_g);
  gemm_part<<<528*2, 128, 0, stream>>>(x, Wt_g, feat_part);
  reduce_softmax<<<MPIX/4, 256, 0, stream>>>(feat_part, bd, depth_ws, img_ws);
  (void)hipMemsetAsync(hist, 0, NKEY * sizeof(int), stream);
  (void)hipMemsetAsync(d_out, 0, (size_t)out_size * sizeof(float), stream);
  geom_k<<<NIMG*NPIX/4, 256, 0, stream>>>(mats, pr, hist);
  scan1_k<<<SCAN_BLKS, 256, 0, stream>>>(hist, blockSums);
  scan2_k<<<1, 512, 0, stream>>>(blockSums, totalK);
  scan3_k<<<SCAN_BLKS, 256, 0, stream>>>(hist, blockSums);
  order_k<<<(P_TOT + 255)/256, 256, 0, stream>>>(pr, hist, sorted);
  gather_seg<<<(P_TOT/CHUNK + 3)/4, 256, 0, stream>>>(sorted, totalK, depth_ws, img_ws, out);
}

// Round 10
// 149.187 us; speedup vs baseline: 7.2357x; 1.0005x over previous
//
#include <hip/hip_runtime.h>

#define NPIX 704
#define NIMG 24
#define NB 4
#define NCAM 6
#define DB 59
#define CT 64
#define P_TOT (NIMG*NPIX*DB)   // 996864
#define NVOX 65536             // 4 batches * 128*128 (gz==0 only)
#define SLC 8                  // histogram slices (contention spreading)
#define NKEY (NVOX*SLC)        // 524288
#define CHUNK 64
#define SCAN_BLKS 512          // NKEY / 1024
#define MPIX (NIMG*NPIX)       // 16896

typedef unsigned short u16;
typedef __attribute__((ext_vector_type(4))) unsigned short u16x4;
typedef __attribute__((ext_vector_type(8))) unsigned short u16x8;
typedef __attribute__((ext_vector_type(8))) __bf16 bf16x8;
typedef __attribute__((ext_vector_type(4))) float f32x4;

__device__ inline u16 f2bf(float f) {          // RN float->bf16
  unsigned u = __float_as_uint(f);
  u += 0x7FFFu + ((u >> 16) & 1u);
  return (u16)(u >> 16);
}
__device__ inline float bf2f(u16 s) {
  return __uint_as_float(((unsigned)s) << 16);
}

// ---------------------------------------------------------------------------
// Kernel 1: W -> bf16 hi/lo (blocks 0..255) + per-(b,n) matrix prep (block 256)
// ---------------------------------------------------------------------------
__device__ inline void inv3(const double a[9], double o[9]) {
  double c0 = a[4]*a[8] - a[5]*a[7];
  double c1 = a[3]*a[8] - a[5]*a[6];
  double c2 = a[3]*a[7] - a[4]*a[6];
  double det = a[0]*c0 - a[1]*c1 + a[2]*c2;
  double id = 1.0 / det;
  o[0] =  c0 * id;
  o[1] = (a[2]*a[7] - a[1]*a[8]) * id;
  o[2] = (a[1]*a[5] - a[2]*a[4]) * id;
  o[3] = -c1 * id;
  o[4] = (a[0]*a[8] - a[2]*a[6]) * id;
  o[5] = (a[2]*a[3] - a[0]*a[5]) * id;
  o[6] =  c2 * id;
  o[7] = (a[1]*a[6] - a[0]*a[7]) * id;
  o[8] = (a[0]*a[4] - a[1]*a[3]) * id;
}

__global__ __launch_bounds__(256) void prep_convw(
    const float* __restrict__ rots, const float* __restrict__ trans,
    const float* __restrict__ intr, const float* __restrict__ prot,
    const float* __restrict__ ptra, float* __restrict__ mats,
    const float* __restrict__ Wd, u16* __restrict__ Wh, u16* __restrict__ Wl) {
  if (blockIdx.x < 256) {
    int idx = blockIdx.x * 256 + threadIdx.x;   // 128*512 entries, idx = o*512+k
    int o = idx >> 9;
    float f = (o < 123) ? Wd[idx - (o << 9) + o * 512] : 0.f;  // == Wd[idx] when o<123
    u16 h = f2bf(f);
    Wh[idx] = h;
    Wl[idx] = f2bf(f - bf2f(h));
    return;
  }
  int bn = threadIdx.x;
  if (bn >= NIMG) return;
  double pr[9], ik[9];
  for (int i = 0; i < 9; i++) { pr[i] = prot[bn*9 + i]; ik[i] = intr[bn*9 + i]; }
  double Minv[9], Kinv[9];
  inv3(pr, Minv);
  inv3(ik, Kinv);
  float* m = mats + bn*24;
  for (int i = 0; i < 9; i++) m[i] = (float)Minv[i];
  float kf[9];
  for (int i = 0; i < 9; i++) kf[i] = (float)Kinv[i];
  {
#pragma clang fp contract(off)
    for (int i = 0; i < 3; i++)
      for (int j = 0; j < 3; j++) {
        float s = rots[bn*9 + i*3 + 0] * kf[0*3 + j];
        s = s + rots[bn*9 + i*3 + 1] * kf[1*3 + j];
        s = s + rots[bn*9 + i*3 + 2] * kf[2*3 + j];
        m[9 + i*3 + j] = s;
      }
  }
  m[18] = ptra[bn*3 + 0]; m[19] = ptra[bn*3 + 1]; m[20] = ptra[bn*3 + 2];
  m[21] = trans[bn*3 + 0]; m[22] = trans[bn*3 + 1]; m[23] = trans[bn*3 + 2];
}

// ---------------------------------------------------------------------------
// Kernel 2: fused MFMA GEMM (bf16 hi/lo 3-term = ~fp32 accurate) + softmax.
// Tile 64 pix x 128 o x K=512, BK=64. 4 waves: 2x2, each 32pix x 64o via
// 2x4 frags of mfma_f32_16x16x32_bf16. XOR-swizzled LDS (both sides).
// LDS map (bytes): Ah[64][72bf16] @0 (9216), Al @9216, Bh[128][72] @18432
// (18432), Bl @36864; total 55296. Epilogue overlays F[64][132] fp32 @0.
// ---------------------------------------------------------------------------
__global__ __launch_bounds__(256) void gemm_fused(const float* __restrict__ x,
    const u16* __restrict__ Wh, const u16* __restrict__ Wl,
    const float* __restrict__ bd,
    float* __restrict__ depth_ws, float* __restrict__ img_ws) {
  __shared__ __attribute__((aligned(16))) unsigned char smem[55296];
  int t = threadIdx.x;
  int l = t & 63, wid = t >> 6;
  int wr = wid >> 1, wc = wid & 1;
  int pixbase = blockIdx.x << 6;       // 704 = 11*64: tile stays in one image
  int bn = pixbase / NPIX;
  int pix0 = pixbase - bn * NPIX;
  const float* xb = x + (size_t)bn * 512 * NPIX + pix0;

  f32x4 zero4 = {0.f, 0.f, 0.f, 0.f};
  f32x4 acc[2][4];
#pragma unroll
  for (int mi = 0; mi < 2; mi++)
#pragma unroll
    for (int ni = 0; ni < 4; ni++) acc[mi][ni] = zero4;

  for (int kb = 0; kb < 512; kb += 64) {
    // ---- stage A: x[64c][64pix] -> Ah/Al[pix][c] (reg 4x4 transpose) ----
    {
      int pixt = (t & 15) << 2;
      int c0 = (t >> 4) << 2;
      float4 v0 = *(const float4*)&xb[(size_t)(kb + c0 + 0) * NPIX + pixt];
      float4 v1 = *(const float4*)&xb[(size_t)(kb + c0 + 1) * NPIX + pixt];
      float4 v2 = *(const float4*)&xb[(size_t)(kb + c0 + 2) * NPIX + pixt];
      float4 v3 = *(const float4*)&xb[(size_t)(kb + c0 + 3) * NPIX + pixt];
      const float* vp[4] = {(const float*)&v0, (const float*)&v1,
                            (const float*)&v2, (const float*)&v3};
#pragma unroll
      for (int j = 0; j < 4; ++j) {
        int row = pixt + j;
        float f0 = vp[0][j], f1 = vp[1][j], f2 = vp[2][j], f3 = vp[3][j];
        u16 h0 = f2bf(f0), h1 = f2bf(f1), h2 = f2bf(f2), h3 = f2bf(f3);
        u16x4 hv = {h0, h1, h2, h3};
        u16x4 lv = {f2bf(f0 - bf2f(h0)), f2bf(f1 - bf2f(h1)),
                    f2bf(f2 - bf2f(h2)), f2bf(f3 - bf2f(h3))};
        int bo = (c0 * 2) ^ ((row & 7) << 4);
        *(u16x4*)(smem + row * 144 + bo) = hv;
        *(u16x4*)(smem + 9216 + row * 144 + bo) = lv;
      }
    }
    // ---- stage B: Wh/Wl[o][k] (k-contiguous) ----
    {
      int o = t & 127;
      int kh = (t >> 7) << 5;            // 0 or 32
      const u16* sh = Wh + (size_t)o * 512 + kb + kh;
      const u16* sl = Wl + (size_t)o * 512 + kb + kh;
#pragma unroll
      for (int i = 0; i < 4; ++i) {
        int kkb = (kh + (i << 3)) * 2;
        int bo = kkb ^ ((o & 7) << 4);
        *(u16x8*)(smem + 18432 + o * 144 + bo) = *(const u16x8*)(sh + (i << 3));
        *(u16x8*)(smem + 36864 + o * 144 + bo) = *(const u16x8*)(sl + (i << 3));
      }
    }
    __syncthreads();
    // ---- compute: 2 k-halves x 2x4 frags x 3 MFMA ----
#pragma unroll
    for (int h = 0; h < 2; ++h) {
      int kk2 = (h * 32 + ((l >> 4) << 3)) * 2;     // byte offset pre-XOR
      bf16x8 ah[2], al2[2];
#pragma unroll
      for (int mi = 0; mi < 2; ++mi) {
        int row = (wr << 5) + (mi << 4) + (l & 15);
        int bo = kk2 ^ ((row & 7) << 4);
        ah[mi]  = *(const bf16x8*)(smem + row * 144 + bo);
        al2[mi] = *(const bf16x8*)(smem + 9216 + row * 144 + bo);
      }
#pragma unroll
      for (int ni = 0; ni < 4; ++ni) {
        int o = (wc << 6) + (ni << 4) + (l & 15);
        int bo = kk2 ^ ((o & 7) << 4);
        bf16x8 bh_ = *(const bf16x8*)(smem + 18432 + o * 144 + bo);
        bf16x8 bl_ = *(const bf16x8*)(smem + 36864 + o * 144 + bo);
#pragma unroll
        for (int mi = 0; mi < 2; ++mi) {
          acc[mi][ni] = __builtin_amdgcn_mfma_f32_16x16x32_bf16(ah[mi], bh_, acc[mi][ni], 0, 0, 0);
          acc[mi][ni] = __builtin_amdgcn_mfma_f32_16x16x32_bf16(ah[mi], bl_, acc[mi][ni], 0, 0, 0);
          acc[mi][ni] = __builtin_amdgcn_mfma_f32_16x16x32_bf16(al2[mi], bh_, acc[mi][ni], 0, 0, 0);
        }
      }
    }
    __syncthreads();
  }

  // ---- epilogue: acc -> F[64][132], then wave softmax ----
  float* F = (float*)smem;
#pragma unroll
  for (int mi = 0; mi < 2; ++mi)
#pragma unroll
    for (int ni = 0; ni < 4; ++ni)
#pragma unroll
      for (int r = 0; r < 4; ++r) {
        int row = (wr << 5) + (mi << 4) + ((l >> 4) << 2) + r;
        int col = (wc << 6) + (ni << 4) + (l & 15);
        F[row * 132 + col] = acc[mi][ni][r];
      }
  __syncthreads();

  int c = l;
  float bA = bd[c];
  float bI = bd[DB + c];
  for (int p = wid; p < 64; p += 4) {
    float fA = F[p * 132 + c] + bA;
    float fI = F[p * 132 + DB + c] + bI;
    float mv = (c < DB) ? fA : -3.4e38f;
#pragma unroll
    for (int ofs = 32; ofs > 0; ofs >>= 1) mv = fmaxf(mv, __shfl_xor(mv, ofs));
    float ev = (c < DB) ? expf(fA - mv) : 0.f;
    float sv = ev;
#pragma unroll
    for (int ofs = 32; ofs > 0; ofs >>= 1) sv += __shfl_xor(sv, ofs);
    size_t rec = (size_t)(pixbase + p) << 6;
    if (c < DB) depth_ws[rec + c] = ev / sv;
    img_ws[rec + c] = fI;
  }
}

// ---------------------------------------------------------------------------
// Kernel 3: geometry -> sliced key + rank via hist atomic.
// ---------------------------------------------------------------------------
__global__ __launch_bounds__(256) void geom_k(const float* __restrict__ mats,
    int2* __restrict__ pr, int* __restrict__ hist) {
  int wid = (blockIdx.x << 2) + (threadIdx.x >> 6);
  int lane = threadIdx.x & 63;
  int bn = wid / NPIX;
  int pix = wid - bn*NPIX;
  int b = bn / NCAM;
  int h = pix / 44, w = pix - h*44;
  const float* M = mats + bn*24;

  int code = -1;
  {
#pragma clang fp contract(off)
    float xs = (float)((double)w * (703.0 / 43.0));
    float ys = (float)(h * 17);
    float dval = (float)(lane + 1);
    float vx = xs - M[18], vy = ys - M[19], vz = dval - M[20];
    float qx = M[0]*vx + M[1]*vy + M[2]*vz;
    float qy = M[3]*vx + M[4]*vy + M[5]*vz;
    float qz = M[6]*vx + M[7]*vy + M[8]*vz;
    float rx = qx*qz, ry = qy*qz;
    float px = M[9]*rx  + M[10]*ry + M[11]*qz + M[21];
    float py = M[12]*rx + M[13]*ry + M[14]*qz + M[22];
    float pz = M[15]*rx + M[16]*ry + M[17]*qz + M[23];
    float gx = floorf((px - (-50.8f - 0.4f)) / 0.8f);
    float gy = floorf((py - (-50.8f - 0.4f)) / 0.8f);
    float gz = floorf((pz - (0.0f - 10.0f)) / 20.0f);
    bool kept = (lane < DB) && (gx >= 0.f) && (gx < 128.f) &&
                (gy >= 0.f) && (gy < 128.f) && (gz == 0.f);
    if (kept) code = (b << 14) + (int)gy * 128 + (int)gx;
  }

  if (lane < DB) {
    int key = -1, r = 0;
    if (code >= 0) {
      key = code * SLC + ((wid + lane) & (SLC - 1));
      r = atomicAdd(&hist[key], 1);
    }
    pr[(size_t)wid * DB + lane] = make_int2(key, r);
  }
}

// ---------------------------------------------------------------------------
// Kernels 4a/4b/4c: hierarchical exclusive scan of hist[NKEY].
// ---------------------------------------------------------------------------
__global__ __launch_bounds__(256) void scan1_k(const int* __restrict__ hist,
    int* __restrict__ blockSums) {
  __shared__ int red[256];
  int t = threadIdx.x;
  const int4* h4 = (const int4*)(hist + (blockIdx.x << 10));
  int4 v = h4[t];
  red[t] = v.x + v.y + v.z + v.w;
  __syncthreads();
  for (int ofs = 128; ofs > 0; ofs >>= 1) {
    if (t < ofs) red[t] += red[t + ofs];
    __syncthreads();
  }
  if (t == 0) blockSums[blockIdx.x] = red[0];
}

__global__ __launch_bounds__(512) void scan2_k(int* __restrict__ blockSums,
    int* __restrict__ totalK) {
  __shared__ int buf[2][512];
  int t = threadIdx.x;
  buf[0][t] = blockSums[t];
  __syncthreads();
  int src = 0;
  for (int ofs = 1; ofs < 512; ofs <<= 1) {
    int v = buf[src][t];
    if (t >= ofs) v += buf[src][t - ofs];
    buf[src ^ 1][t] = v;
    __syncthreads();
    src ^= 1;
  }
  blockSums[t] = (t == 0) ? 0 : buf[src][t - 1];
  if (t == 511) *totalK = buf[src][511];
}

__global__ __launch_bounds__(256) void scan3_k(int* __restrict__ hist,
    const int* __restrict__ blockSums) {
  __shared__ int buf[2][256];
  int t = threadIdx.x;
  int4* h4 = (int4*)(hist + (blockIdx.x << 10));
  int4 v = h4[t];
  int s = v.x + v.y + v.z + v.w;
  buf[0][t] = s;
  __syncthreads();
  int src = 0;
  for (int ofs = 1; ofs < 256; ofs <<= 1) {
    int vv = buf[src][t];
    if (t >= ofs) vv += buf[src][t - ofs];
    buf[src ^ 1][t] = vv;
    __syncthreads();
    src ^= 1;
  }
  int run = blockSums[blockIdx.x] + ((t == 0) ? 0 : buf[src][t - 1]);
  int4 o;
  o.x = run; run += v.x;
  o.y = run; run += v.y;
  o.z = run; run += v.z;
  o.w = run;
  h4[t] = o;
}

// ---------------------------------------------------------------------------
// Kernel 5: atomic-free placement: pos = offsets[key] + rank.
// ---------------------------------------------------------------------------
__global__ __launch_bounds__(256) void order_k(const int2* __restrict__ pr,
    const int* __restrict__ offsets, int2* __restrict__ sorted) {
  int p = blockIdx.x * 256 + threadIdx.x;
  if (p >= P_TOT) return;
  int2 e = pr[p];
  if (e.x >= 0) {
    int pos = offsets[e.x] + e.y;
    int bnpix = p / DB;
    int d = p - bnpix * DB;
    sorted[pos] = make_int2(e.x / SLC, (bnpix << 6) + d);
  }
}

// ---------------------------------------------------------------------------
// Kernel 6: segmented gather. One wave per CHUNK sorted points; lane = channel.
// ---------------------------------------------------------------------------
__global__ __launch_bounds__(256) void gather_seg(const int2* __restrict__ sorted,
    const int* __restrict__ totalK,
    const float* __restrict__ depth_ws, const float* __restrict__ img_ws,
    float* __restrict__ out) {
  int wid = (blockIdx.x << 2) + (threadIdx.x >> 6);
  int lane = threadIdx.x & 63;
  int K = *totalK;
  int start = wid * CHUNK;
  if (start >= K) return;
  int end = min(start + CHUNK, K);

  int2 s0 = sorted[start];
  int cur = s0.x;
  float acc = 0.f;
  for (int i = start; i < end; ++i) {
    int2 s = sorted[i];
    if (s.x != cur) {                     // wave-uniform branch
      int b = cur >> 14, vox = cur & 16383;
      unsafeAtomicAdd(&out[((size_t)((b << 6) + lane) << 14) + vox], acc);
      acc = 0.f;
      cur = s.x;
    }
    float dep = depth_ws[s.y];                          // broadcast load
    float im  = img_ws[(s.y & 0x7FFFFFC0) + lane];      // coalesced 256B
    acc += dep * im;
  }
  int b = cur >> 14, vox = cur & 16383;
  unsafeAtomicAdd(&out[((size_t)((b << 6) + lane) << 14) + vox], acc);
}

// ---------------------------------------------------------------------------
extern "C" void kernel_launch(void* const* d_in, const int* in_sizes, int n_in,
                              void* d_out, int out_size, void* d_ws, size_t ws_size,
                              hipStream_t stream) {
  const float* x    = (const float*)d_in[0];
  const float* rots = (const float*)d_in[1];
  const float* trn  = (const float*)d_in[2];
  const float* intr = (const float*)d_in[3];
  const float* prot = (const float*)d_in[4];
  const float* ptra = (const float*)d_in[5];
  const float* Wd   = (const float*)d_in[6];
  const float* bd   = (const float*)d_in[7];
  float* out = (float*)d_out;
  float* ws  = (float*)d_ws;

  // Layout identical in extent to the validated round-6/8/9 footprint.
  float* mats     = ws;                                    // 1024 floats
  float* depth_ws = ws + 1024;                             // 1,081,344
  float* img_ws   = depth_ws + (size_t)MPIX*64;            // 1,081,344
  int*   hist     = (int*)(img_ws + (size_t)MPIX*64);      // 524,288 (16B-aligned)
  int*   blockSums= hist + NKEY;                           // 512
  int*   totalK   = blockSums + 512;                       // 4 (pad)
  int2*  pr       = (int2*)(totalK + 4);                   // 996,864 int2
  int2*  sorted   = pr + P_TOT;                            // 996,864 int2
  // Wh/Wl (512 KB) alias the head of hist's 2 MB: read only by gemm_fused,
  // which completes (stream order) before the hist memset below.
  u16*   Wh       = (u16*)hist;                            // 65,536 u16
  u16*   Wl       = Wh + 65536;                            // 65,536 u16

  prep_convw<<<257, 256, 0, stream>>>(rots, trn, intr, prot, ptra, mats, Wd, Wh, Wl);
  gemm_fused<<<MPIX/64, 256, 0, stream>>>(x, Wh, Wl, bd, depth_ws, img_ws);
  (void)hipMemsetAsync(hist, 0, NKEY * sizeof(int), stream);
  (void)hipMemsetAsync(d_out, 0, (size_t)out_size * sizeof(float), stream);
  geom_k<<<NIMG*NPIX/4, 256, 0, stream>>>(mats, pr, hist);
  scan1_k<<<SCAN_BLKS, 256, 0, stream>>>(hist, blockSums);
  scan2_k<<<1, 512, 0, stream>>>(blockSums, totalK);
  scan3_k<<<SCAN_BLKS, 256, 0, stream>>>(hist, blockSums);
  order_k<<<(P_TOT + 255)/256, 256, 0, stream>>>(pr, hist, sorted);
  gather_seg<<<(P_TOT/CHUNK + 3)/4, 256, 0, stream>>>(sorted, totalK, depth_ws, img_ws, out);
}